// Round 2
// baseline (2973.793 us; speedup 1.0000x reference)
//
#include <hip/hip_runtime.h>
#include <hip/hip_bf16.h>
#include <cstdint>
#include <cstddef>

typedef unsigned short u16;
typedef __attribute__((ext_vector_type(4))) float f32x4;
typedef __attribute__((ext_vector_type(8))) short bf16x8;
typedef __attribute__((ext_vector_type(8))) unsigned short u16x8;
typedef __attribute__((ext_vector_type(4))) unsigned short u16x4;

#define D_LAYERS 8
#define DIMN 1024
#define FFD 4096
#define VOCAB 32000
#define MROWS 4096   /* B*S */
#define SEQ 2048
#define NCHUNK 64
#define LCHUNK 32

// ---------- helpers ----------
__device__ __forceinline__ u16 f2b(float f) {
  union { float f; unsigned u; } v; v.f = f;
  unsigned r = v.u + 0x7FFFu + ((v.u >> 16) & 1u);
  return (u16)(r >> 16);
}
__device__ __forceinline__ float b2f(u16 h) {
  union { unsigned u; float f; } v; v.u = ((unsigned)h) << 16;
  return v.f;
}
__device__ __forceinline__ float sigm(float x) { return 1.f / (1.f + __expf(-x)); }

// async global->LDS, 16B per lane. LDS dest is wave-uniform base + lane*16 (HW).
__device__ __forceinline__ void async16(const void* g, void* l) {
  auto gp = reinterpret_cast<const __attribute__((address_space(1))) char*>(
      reinterpret_cast<uintptr_t>(g));
  auto lp = reinterpret_cast<__attribute__((address_space(3))) char*>(
      reinterpret_cast<uintptr_t>(l));
  __builtin_amdgcn_global_load_lds(gp, lp, 16, 0, 0);
}

__device__ __forceinline__ float blk_sum(float v) {
  __shared__ float sm[4];
  #pragma unroll
  for (int o = 32; o > 0; o >>= 1) v += __shfl_xor(v, o);
  if ((threadIdx.x & 63) == 0) sm[threadIdx.x >> 6] = v;
  __syncthreads();
  float r = sm[0] + sm[1] + sm[2] + sm[3];
  __syncthreads();
  return r;
}

// ---------- small kernels ----------
__global__ __launch_bounds__(256) void k_cvt(const f32x4* __restrict__ in,
                                             u16x8* __restrict__ out) {
  size_t i = (size_t)blockIdx.x * 256 + threadIdx.x;
  f32x4 a = in[i * 2], b = in[i * 2 + 1];
  u16x8 o;
  o[0] = f2b(a[0]); o[1] = f2b(a[1]); o[2] = f2b(a[2]); o[3] = f2b(a[3]);
  o[4] = f2b(b[0]); o[5] = f2b(b[1]); o[6] = f2b(b[2]); o[7] = f2b(b[3]);
  out[i] = o;
}

__global__ __launch_bounds__(256) void k_embed(const int* __restrict__ tok,
                                               const float* __restrict__ emb,
                                               float* __restrict__ x) {
  const int r = blockIdx.x;
  const int tk = tok[r];
  f32x4 v = ((const f32x4*)(emb + (size_t)tk * DIMN))[threadIdx.x];
  float ss = v[0]*v[0] + v[1]*v[1] + v[2]*v[2] + v[3]*v[3];
  float tot = blk_sum(ss);
  float nrm = sqrtf(tot);
  float s = (nrm > 1.f) ? (1.f / (nrm + 1e-7f)) : 1.f;
  f32x4 o = {v[0]*s, v[1]*s, v[2]*s, v[3]*s};
  ((f32x4*)(x + (size_t)r * DIMN))[threadIdx.x] = o;
}

__global__ __launch_bounds__(256) void k_rms(const float* __restrict__ x,
                                             const float* __restrict__ wgt,
                                             u16* __restrict__ out) {
  const int r = blockIdx.x;
  f32x4 v = ((const f32x4*)(x + (size_t)r * DIMN))[threadIdx.x];
  float ss = v[0]*v[0] + v[1]*v[1] + v[2]*v[2] + v[3]*v[3];
  float tot = blk_sum(ss);
  float sc = rsqrtf(tot * (1.f / DIMN) + 1e-6f);
  f32x4 w = ((const f32x4*)wgt)[threadIdx.x];
  u16x4 o;
  o[0] = f2b(v[0] * sc * w[0]);
  o[1] = f2b(v[1] * sc * w[1]);
  o[2] = f2b(v[2] * sc * w[2]);
  o[3] = f2b(v[3] * sc * w[3]);
  ((u16x4*)(out + (size_t)r * DIMN))[threadIdx.x] = o;
}

// scan phase A: per-chunk aggregates (A = prod f, V = chunk-local scan end)
__global__ __launch_bounds__(256) void k_scanA(const float* __restrict__ f,
                                               const float* __restrict__ ti,
                                               const float* __restrict__ gg,
                                               float* __restrict__ Ac,
                                               float* __restrict__ Vc) {
  const int bx = blockIdx.x;              // b*256 + c*4 + dg
  const int dg = bx & 3, c = (bx >> 2) & 63, b = bx >> 8;
  const int d = dg * 256 + threadIdx.x;
  const size_t base = ((size_t)(b * SEQ + c * LCHUNK)) * DIMN + d;
  float a = 1.f, h = 0.f;
  #pragma unroll 4
  for (int t = 0; t < LCHUNK; ++t) {
    size_t ix = base + (size_t)t * DIMN;
    float fv = f[ix];
    float vv = ti[ix] * gg[ix];
    h = fv * h + vv;
    a *= fv;
  }
  const size_t ci = ((size_t)(b * NCHUNK + c)) * DIMN + d;
  Ac[ci] = a; Vc[ci] = h;
}

// scan phase B: exclusive scan over chunks, init = h0
__global__ __launch_bounds__(256) void k_scanB(const float* __restrict__ Ac,
                                               const float* __restrict__ Vc,
                                               const float* __restrict__ h0,
                                               float* __restrict__ carry) {
  const int idx = blockIdx.x * 256 + threadIdx.x;  // 0..2047
  const int b = idx >> 10, d = idx & 1023;
  float h = h0[d];
  for (int c = 0; c < NCHUNK; ++c) {
    size_t ci = ((size_t)(b * NCHUNK + c)) * DIMN + d;
    carry[ci] = h;
    h = Ac[ci] * h + Vc[ci];
  }
}

// scan phase C: recompute with carry-in, y = tanh(h)*sig(og), x += y
__global__ __launch_bounds__(256) void k_scanC(const float* __restrict__ f,
                                               const float* __restrict__ ti,
                                               const float* __restrict__ gg,
                                               const float* __restrict__ oo,
                                               const float* __restrict__ carry,
                                               float* __restrict__ x) {
  const int bx = blockIdx.x;
  const int dg = bx & 3, c = (bx >> 2) & 63, b = bx >> 8;
  const int d = dg * 256 + threadIdx.x;
  const size_t base = ((size_t)(b * SEQ + c * LCHUNK)) * DIMN + d;
  float h = carry[((size_t)(b * NCHUNK + c)) * DIMN + d];
  for (int t = 0; t < LCHUNK; ++t) {
    size_t ix = base + (size_t)t * DIMN;
    float fv = f[ix];
    h = fv * h + ti[ix] * gg[ix];
    float y = tanhf(h) * oo[ix];
    x[ix] += y;
  }
}

// ---------- 128-tile GEMM (m97 structure, proven round 1) ----------
constexpr int EPI_GATES = 0, EPI_SILU_BF = 1, EPI_MUL_BF = 2, EPI_RES_F32 = 3,
              EPI_BIAS_F32 = 4;

template<int BN_T, int EPI>
__global__ __launch_bounds__(256, 2)
void gemm_bt(const u16* __restrict__ A,
             const u16* __restrict__ B0, const u16* __restrict__ B1,
             const u16* __restrict__ B2, const u16* __restrict__ B3,
             const float* __restrict__ bias0, const float* __restrict__ bias1,
             const float* __restrict__ bias2, const float* __restrict__ bias3,
             float* __restrict__ oF0, float* __restrict__ oF1,
             float* __restrict__ oF2, float* __restrict__ oF3,
             u16* __restrict__ oB,
             const u16* __restrict__ exB, const float* __restrict__ exF,
             int N, int K)
{
  constexpr int MF = (BN_T == 128) ? 4 : 2;
  constexpr int WAVES_N = (BN_T == 128) ? 2 : 1;
  constexpr int ISS_B = BN_T / 32;
  __shared__ __align__(16) u16 As[128 * 64];
  __shared__ __align__(16) u16 Bs[BN_T * 64];
  const int tid = threadIdx.x;
  const int w = tid >> 6, lane = tid & 63;
  const int wm = w / WAVES_N, wn = w % WAVES_N;
  const int m0 = blockIdx.x * 128;
  const int n0 = blockIdx.y * BN_T;
  const int z = blockIdx.z;

  const u16* Bw;
  const float* bias;
  float* oF;
  if constexpr (EPI == EPI_GATES) {
    Bw   = (z == 0) ? B0 : (z == 1) ? B1 : (z == 2) ? B2 : B3;
    bias = (z == 0) ? bias0 : (z == 1) ? bias1 : (z == 2) ? bias2 : bias3;
    oF   = (z == 0) ? oF0 : (z == 1) ? oF1 : (z == 2) ? oF2 : oF3;
  } else {
    Bw = B0; bias = bias0; oF = oF0;
  }

  const f32x4 zero = {0.f, 0.f, 0.f, 0.f};
  f32x4 acc[MF][4];
  #pragma unroll
  for (int mf = 0; mf < MF; ++mf)
    #pragma unroll
    for (int nf = 0; nf < 4; ++nf) acc[mf][nf] = zero;

  for (int kt = 0; kt < K; kt += 64) {
    #pragma unroll
    for (int i = 0; i < 4; ++i) {
      int p = i * 4096 + w * 1024 + lane * 16;
      int r = p >> 7;
      int cs = (p & 127) ^ ((r & 7) << 4);
      async16(A + ((size_t)(m0 + r) * K + kt) + (cs >> 1),
              (char*)As + i * 4096 + w * 1024);
    }
    #pragma unroll
    for (int i = 0; i < ISS_B; ++i) {
      int p = i * 4096 + w * 1024 + lane * 16;
      int r = p >> 7;
      int cs = (p & 127) ^ ((r & 7) << 4);
      async16(Bw + ((size_t)(n0 + r) * K + kt) + (cs >> 1),
              (char*)Bs + i * 4096 + w * 1024);
    }
    __syncthreads();
    #pragma unroll
    for (int ks = 0; ks < 2; ++ks) {
      bf16x8 av[MF], bv[4];
      const int cbase = ks * 64 + ((lane >> 4) << 4);
      #pragma unroll
      for (int mf = 0; mf < MF; ++mf) {
        int r = wm * (MF * 16) + mf * 16 + (lane & 15);
        av[mf] = *(const bf16x8*)((const char*)As + r * 128 + (cbase ^ ((r & 7) << 4)));
      }
      #pragma unroll
      for (int nf = 0; nf < 4; ++nf) {
        int r = wn * 64 + nf * 16 + (lane & 15);
        bv[nf] = *(const bf16x8*)((const char*)Bs + r * 128 + (cbase ^ ((r & 7) << 4)));
      }
      #pragma unroll
      for (int mf = 0; mf < MF; ++mf)
        #pragma unroll
        for (int nf = 0; nf < 4; ++nf)
          acc[mf][nf] = __builtin_amdgcn_mfma_f32_16x16x32_bf16(
              av[mf], bv[nf], acc[mf][nf], 0, 0, 0);
    }
    __syncthreads();
  }

  #pragma unroll
  for (int nf = 0; nf < 4; ++nf) {
    const int n = n0 + wn * 64 + nf * 16 + (lane & 15);
    const float bb = bias[n];
    #pragma unroll
    for (int mf = 0; mf < MF; ++mf) {
      #pragma unroll
      for (int j = 0; j < 4; ++j) {
        const int m = m0 + wm * (MF * 16) + mf * 16 + ((lane >> 4) << 2) + j;
        const size_t idx = (size_t)m * N + n;
        float v = acc[mf][nf][j] + bb;
        if constexpr (EPI == EPI_GATES) {
          oF[idx] = (z == 1) ? tanhf(v) : sigm(v);
        } else if constexpr (EPI == EPI_SILU_BF) {
          oB[idx] = f2b(v * sigm(v));
        } else if constexpr (EPI == EPI_MUL_BF) {
          oB[idx] = f2b(v * b2f(exB[idx]));
        } else if constexpr (EPI == EPI_RES_F32) {
          oF[idx] = v + exF[idx];
        } else {
          oF[idx] = v;
        }
      }
    }
  }
}

// ---------- 256-tile 8-phase GEMM (T2+T3+T4+T5, counted vmcnt) ----------
// C = A[M,K] @ B[N,K]^T. 512 thr = 8 waves (2M x 4N); per-wave 128x64 out.
// LDS: 2 bufs x (A 32KB + B 32KB) = 128KB. Per K-tile staging = 64 x 1KB
// issues split 8/wave: 6 "early" (all B + A rows 0-63) + 2 "late" (A rows
// 64-127). Waits: vmcnt(4) before phase2 (covers late), vmcnt(2) at tile end
// (covers next tile's early). Each wait precedes a barrier -> cross-wave safe.
constexpr int EG4 = 0, ESILU = 1, EMUL = 2, EVOC = 3;

template<int EPI>
__global__ __launch_bounds__(512, 2)
void gemm256(const u16* __restrict__ A, const u16* __restrict__ Bm,
             const float* __restrict__ b0, const float* __restrict__ b1,
             const float* __restrict__ b2, const float* __restrict__ b3,
             float* __restrict__ f0, float* __restrict__ f1,
             float* __restrict__ f2, float* __restrict__ f3,
             u16* __restrict__ oB, const u16* __restrict__ exB,
             float* __restrict__ oF,
             int N, int K, int GX)
{
  __shared__ __align__(16) char lds[131072];
  const int tid = threadIdx.x;
  const int w = tid >> 6, lane = tid & 63;
  const int wm = w >> 2, wn = w & 3;
  // XCD-aware swizzle (all grids here are %8==0)
  const int nwg = gridDim.x, bid = blockIdx.x;
  const int swz = (bid & 7) * (nwg >> 3) + (bid >> 3);
  const int m0 = (swz % GX) * 256;
  const int n0 = (swz / GX) * 256;

  // staging plan: LDS-byte (within 64KB buf) of each of this wave's 8 issues
  int Dj[8];
  #pragma unroll
  for (int j = 0; j < 6; ++j) {
    const int e = w * 6 + j;      // 0..31: B (all early); 32..47: A rows 0-63
    Dj[j] = (e < 32) ? (32768 + (e << 10))
                     : ((((e - 32) >> 3) << 14) + (((e - 32) & 7) << 10));
  }
  #pragma unroll
  for (int j = 0; j < 2; ++j) {   // late: A rows 64-127 of both halves
    const int l = (w << 1) + j;
    Dj[6 + j] = ((l >> 3) << 14) + 8192 + ((l & 7) << 10);
  }

  auto issue = [&](int buf, int j, int kt) {
    const int d = Dj[j];
    const int qq = d + (lane << 4);
    const int row = (qq & 32767) >> 7;           // tile-local row 0..255
    const int cs = (qq & 127) ^ ((row & 7) << 4);
    const u16* src = (qq >> 15)
        ? (Bm + ((size_t)(n0 + row) * K + kt) + (cs >> 1))
        : (A  + ((size_t)(m0 + row) * K + kt) + (cs >> 1));
    async16(src, lds + (buf << 16) + d);
  };
  auto rdA = [&](int buf, int mf, int ks) -> bf16x8 {
    const int row = wm * 128 + mf * 16 + (lane & 15);
    const int col = (ks * 64 + ((lane >> 4) << 4)) ^ ((row & 7) << 4);
    return *(const bf16x8*)(lds + (buf << 16) + row * 128 + col);
  };
  auto rdB = [&](int buf, int nf, int ks) -> bf16x8 {
    const int row = wn * 64 + nf * 16 + (lane & 15);
    const int col = (ks * 64 + ((lane >> 4) << 4)) ^ ((row & 7) << 4);
    return *(const bf16x8*)(lds + (buf << 16) + 32768 + row * 128 + col);
  };

  const f32x4 zero = {0.f, 0.f, 0.f, 0.f};
  f32x4 acc[8][4];
  #pragma unroll
  for (int mf = 0; mf < 8; ++mf)
    #pragma unroll
    for (int nf = 0; nf < 4; ++nf) acc[mf][nf] = zero;
  bf16x8 av[4][2], bv[2][2];

#define MM256(MFO, NFO)                                                    \
  __builtin_amdgcn_s_setprio(1);                                           \
  _Pragma("unroll")                                                        \
  for (int mf = 0; mf < 4; ++mf)                                           \
    _Pragma("unroll")                                                      \
    for (int nf = 0; nf < 2; ++nf)                                         \
      _Pragma("unroll")                                                    \
      for (int ks = 0; ks < 2; ++ks)                                       \
        acc[(MFO) + mf][(NFO) + nf] = __builtin_amdgcn_mfma_f32_16x16x32_bf16( \
            av[mf][ks], bv[nf][ks], acc[(MFO) + mf][(NFO) + nf], 0, 0, 0); \
  __builtin_amdgcn_s_setprio(0);

  const int NT = K >> 6;
  // prologue: stage tile 0, wait early-6, go
  #pragma unroll
  for (int j = 0; j < 8; ++j) issue(0, j, 0);
  asm volatile("s_waitcnt vmcnt(2)" ::: "memory");
  __builtin_amdgcn_s_barrier();

  for (int t = 0; t < NT; ++t) {
    const int buf = t & 1, nbuf = buf ^ 1;
    const bool pf = (t + 1 < NT);
    const int kn = (t + 1) << 6;

    // ---- phase 0: A mf0-3 + B nf0-1 ----
    #pragma unroll
    for (int mf = 0; mf < 4; ++mf) { av[mf][0] = rdA(buf, mf, 0); av[mf][1] = rdA(buf, mf, 1); }
    #pragma unroll
    for (int nf = 0; nf < 2; ++nf) { bv[nf][0] = rdB(buf, nf, 0); bv[nf][1] = rdB(buf, nf, 1); }
    if (pf) { issue(nbuf, 0, kn); issue(nbuf, 1, kn); }
    __builtin_amdgcn_s_barrier();
    asm volatile("s_waitcnt lgkmcnt(0)" ::: "memory");
    MM256(0, 0)
    __builtin_amdgcn_s_barrier();

    // ---- phase 1: B nf2-3 ----
    #pragma unroll
    for (int nf = 0; nf < 2; ++nf) { bv[nf][0] = rdB(buf, 2 + nf, 0); bv[nf][1] = rdB(buf, 2 + nf, 1); }
    if (pf) { issue(nbuf, 2, kn); issue(nbuf, 3, kn); }
    __builtin_amdgcn_s_barrier();
    asm volatile("s_waitcnt lgkmcnt(0)" ::: "memory");
    MM256(0, 2)
    if (pf) asm volatile("s_waitcnt vmcnt(4)" ::: "memory");  // late(t) done
    else    asm volatile("s_waitcnt vmcnt(0)" ::: "memory");
    __builtin_amdgcn_s_barrier();

    // ---- phase 2: A mf4-7 (late rows) ----
    #pragma unroll
    for (int mf = 0; mf < 4; ++mf) { av[mf][0] = rdA(buf, 4 + mf, 0); av[mf][1] = rdA(buf, 4 + mf, 1); }
    if (pf) { issue(nbuf, 4, kn); issue(nbuf, 5, kn); }
    __builtin_amdgcn_s_barrier();
    asm volatile("s_waitcnt lgkmcnt(0)" ::: "memory");
    MM256(4, 2)
    __builtin_amdgcn_s_barrier();

    // ---- phase 3: B nf0-1 again ----
    #pragma unroll
    for (int nf = 0; nf < 2; ++nf) { bv[nf][0] = rdB(buf, nf, 0); bv[nf][1] = rdB(buf, nf, 1); }
    if (pf) { issue(nbuf, 6, kn); issue(nbuf, 7, kn); }
    __builtin_amdgcn_s_barrier();
    asm volatile("s_waitcnt lgkmcnt(0)" ::: "memory");
    MM256(4, 0)
    if (pf) asm volatile("s_waitcnt vmcnt(2)" ::: "memory");  // early(t+1) done
    __builtin_amdgcn_s_barrier();
  }
#undef MM256

  // epilogue: C/D map col=lane&15, row=(lane>>4)*4+j
  if constexpr (EPI == EG4) {
    const int z = n0 >> 10;  // uniform per block
    const float* bz = (z == 0) ? b0 : (z == 1) ? b1 : (z == 2) ? b2 : b3;
    float* fz = (z == 0) ? f0 : (z == 1) ? f1 : (z == 2) ? f2 : f3;
    #pragma unroll
    for (int nf = 0; nf < 4; ++nf) {
      const int n = (n0 & 1023) + wn * 64 + nf * 16 + (lane & 15);
      const float bb = bz[n];
      #pragma unroll
      for (int mf = 0; mf < 8; ++mf)
        #pragma unroll
        for (int j = 0; j < 4; ++j) {
          const int m = m0 + wm * 128 + mf * 16 + ((lane >> 4) << 2) + j;
          float v = acc[mf][nf][j] + bb;
          fz[(size_t)m * 1024 + n] = (z == 1) ? tanhf(v) : sigm(v);
        }
    }
  } else {
    #pragma unroll
    for (int nf = 0; nf < 4; ++nf) {
      const int n = n0 + wn * 64 + nf * 16 + (lane & 15);
      const float bb = b0[n];
      #pragma unroll
      for (int mf = 0; mf < 8; ++mf)
        #pragma unroll
        for (int j = 0; j < 4; ++j) {
          const int m = m0 + wm * 128 + mf * 16 + ((lane >> 4) << 2) + j;
          const size_t idx = (size_t)m * N + n;
          float v = acc[mf][nf][j] + bb;
          if constexpr (EPI == ESILU) {
            oB[idx] = f2b(v * sigm(v));
          } else if constexpr (EPI == EMUL) {
            oB[idx] = f2b(v * b2f(exB[idx]));
          } else {
            oF[idx] = v;
          }
        }
    }
  }
}

// ---------- launcher ----------
extern "C" void kernel_launch(void* const* d_in, const int* in_sizes, int n_in,
                              void* d_out, int out_size, void* d_ws, size_t ws_size,
                              hipStream_t stream) {
  (void)in_sizes; (void)n_in; (void)out_size; (void)ws_size;
  const int*   tokens = (const int*)d_in[0];
  const float* emb  = (const float*)d_in[1];
  const float* h0   = (const float*)d_in[2];
  const float* Wf   = (const float*)d_in[3];
  const float* bf_  = (const float*)d_in[4];
  const float* Wi   = (const float*)d_in[5];
  const float* bi_  = (const float*)d_in[6];
  const float* Wig  = (const float*)d_in[7];
  const float* big_ = (const float*)d_in[8];
  const float* Wog  = (const float*)d_in[9];
  const float* bog_ = (const float*)d_in[10];
  const float* n1   = (const float*)d_in[11];
  const float* n2   = (const float*)d_in[12];
  const float* Wfc  = (const float*)d_in[13];
  const float* bfc_ = (const float*)d_in[14];
  const float* Wfa  = (const float*)d_in[15];
  const float* bfa_ = (const float*)d_in[16];
  const float* Wfo  = (const float*)d_in[17];
  const float* bfo_ = (const float*)d_in[18];
  const float* nl_  = (const float*)d_in[19];
  const float* Wout = (const float*)d_in[20];
  const float* bout_= (const float*)d_in[21];
  float* out = (float*)d_out;

  char* p = (char*)d_ws;
  auto alloc = [&](size_t bytes) {
    char* r = p; p += (bytes + 255) & ~(size_t)255; return r;
  };
  u16* wbGates = (u16*)alloc((size_t)4 * DIMN * DIMN * 2);  // [4*1024,1024]
  u16* wbWfc  = (u16*)alloc((size_t)FFD * DIMN * 2);
  u16* wbWfa  = (u16*)alloc((size_t)FFD * DIMN * 2);
  u16* wbWfo  = (u16*)alloc((size_t)FFD * DIMN * 2);
  u16* wbWout = (u16*)alloc((size_t)VOCAB * DIMN * 2);
  float* x    = (float*)alloc((size_t)MROWS * DIMN * 4);
  u16* hin    = (u16*)alloc((size_t)MROWS * DIMN * 2);
  float* fbuf = (float*)alloc((size_t)MROWS * DIMN * 4);
  float* tibuf= (float*)alloc((size_t)MROWS * DIMN * 4);
  float* ggbuf= (float*)alloc((size_t)MROWS * DIMN * 4);
  float* oobuf= (float*)alloc((size_t)MROWS * DIMN * 4);
  // FFN intermediates alias the (then-dead) gate buffers:
  u16* sa = (u16*)fbuf;                                   // [4096,4096] bf16
  u16* ub = (u16*)((char*)fbuf + (size_t)MROWS * FFD * 2);// [4096,4096] bf16
  float* Ac    = (float*)alloc((size_t)2 * NCHUNK * DIMN * 4);
  float* Vc    = (float*)alloc((size_t)2 * NCHUNK * DIMN * 4);
  float* carry = (float*)alloc((size_t)2 * NCHUNK * DIMN * 4);

  auto cvt = [&](const float* src, u16* dst, size_t nelem) {
    k_cvt<<<dim3((unsigned)(nelem / 2048)), dim3(256), 0, stream>>>(
        (const f32x4*)src, (u16x8*)dst);
  };

  k_embed<<<dim3(MROWS), dim3(256), 0, stream>>>(tokens, emb, x);

  for (int L = 0; L < D_LAYERS; ++L) {
    const size_t oDD = (size_t)L * DIMN * DIMN;
    const size_t oFD = (size_t)L * FFD * DIMN;
    cvt(Wf  + oDD, wbGates + (size_t)0 * DIMN * DIMN, (size_t)DIMN * DIMN);
    cvt(Wi  + oDD, wbGates + (size_t)1 * DIMN * DIMN, (size_t)DIMN * DIMN);
    cvt(Wig + oDD, wbGates + (size_t)2 * DIMN * DIMN, (size_t)DIMN * DIMN);
    cvt(Wog + oDD, wbGates + (size_t)3 * DIMN * DIMN, (size_t)DIMN * DIMN);
    cvt(Wfc + oFD, wbWfc, (size_t)FFD * DIMN);
    cvt(Wfa + oFD, wbWfa, (size_t)FFD * DIMN);
    cvt(Wfo + oFD, wbWfo, (size_t)FFD * DIMN);

    k_rms<<<dim3(MROWS), dim3(256), 0, stream>>>(x, n1 + (size_t)L * DIMN, hin);

    // fused 4-gate GEMM: [4096,1024] @ [4096,1024]^T, route by n>>10
    gemm256<EG4><<<dim3(256), dim3(512), 0, stream>>>(
        hin, wbGates,
        bf_ + (size_t)L * DIMN, bi_ + (size_t)L * DIMN,
        big_ + (size_t)L * DIMN, bog_ + (size_t)L * DIMN,
        fbuf, tibuf, ggbuf, oobuf,
        nullptr, nullptr, nullptr, 4096, DIMN, 16);

    k_scanA<<<dim3(512), dim3(256), 0, stream>>>(fbuf, tibuf, ggbuf, Ac, Vc);
    k_scanB<<<dim3(8), dim3(256), 0, stream>>>(Ac, Vc, h0 + (size_t)L * DIMN, carry);
    k_scanC<<<dim3(512), dim3(256), 0, stream>>>(fbuf, tibuf, ggbuf, oobuf, carry, x);

    k_rms<<<dim3(MROWS), dim3(256), 0, stream>>>(x, n2 + (size_t)L * DIMN, hin);

    gemm256<ESILU><<<dim3(256), dim3(512), 0, stream>>>(
        hin, wbWfa,
        bfa_ + (size_t)L * FFD, nullptr, nullptr, nullptr,
        nullptr, nullptr, nullptr, nullptr,
        sa, nullptr, nullptr, FFD, DIMN, 16);

    gemm256<EMUL><<<dim3(256), dim3(512), 0, stream>>>(
        hin, wbWfc,
        bfc_ + (size_t)L * FFD, nullptr, nullptr, nullptr,
        nullptr, nullptr, nullptr, nullptr,
        ub, sa, nullptr, FFD, DIMN, 16);

    gemm_bt<128, EPI_RES_F32><<<dim3(32, 8), dim3(256), 0, stream>>>(
        ub, wbWfo, nullptr, nullptr, nullptr,
        bfo_ + (size_t)L * DIMN, nullptr, nullptr, nullptr,
        x, nullptr, nullptr, nullptr,
        nullptr, nullptr, x, DIMN, FFD);
  }

  cvt(Wout, wbWout, (size_t)VOCAB * DIMN);
  k_rms<<<dim3(MROWS), dim3(256), 0, stream>>>(x, nl_, hin);
  gemm256<EVOC><<<dim3(2000), dim3(512), 0, stream>>>(
      hin, wbWout,
      bout_, nullptr, nullptr, nullptr,
      nullptr, nullptr, nullptr, nullptr,
      nullptr, nullptr, out, VOCAB, DIMN, 16);
}

// Round 3
// 2738.203 us; speedup vs baseline: 1.0860x; 1.0860x over previous
//
#include <hip/hip_runtime.h>
#include <hip/hip_bf16.h>
#include <cstdint>
#include <cstddef>

typedef unsigned short u16;
typedef __attribute__((ext_vector_type(4))) float f32x4;
typedef __attribute__((ext_vector_type(8))) short bf16x8;
typedef __attribute__((ext_vector_type(8))) unsigned short u16x8;
typedef __attribute__((ext_vector_type(4))) unsigned short u16x4;

#define D_LAYERS 8
#define DIMN 1024
#define FFD 4096
#define VOCAB 32000
#define MROWS 4096   /* B*S */
#define SEQ 2048
#define NCHUNK 64
#define LCHUNK 32

// ---------- helpers ----------
__device__ __forceinline__ u16 f2b(float f) {
  union { float f; unsigned u; } v; v.f = f;
  unsigned r = v.u + 0x7FFFu + ((v.u >> 16) & 1u);
  return (u16)(r >> 16);
}
__device__ __forceinline__ float b2f(u16 h) {
  union { unsigned u; float f; } v; v.u = ((unsigned)h) << 16;
  return v.f;
}
__device__ __forceinline__ float sigm(float x) { return 1.f / (1.f + __expf(-x)); }
__device__ __forceinline__ float ftanh(float x) {
  float e = __expf(2.f * x);          // inf for large x -> 1; 0 for very neg -> -1
  return 1.f - 2.f / (e + 1.f);
}

// async global->LDS, 16B per lane. LDS dest is wave-uniform base + lane*16 (HW).
__device__ __forceinline__ void async16(const void* g, void* l) {
  auto gp = reinterpret_cast<const __attribute__((address_space(1))) char*>(
      reinterpret_cast<uintptr_t>(g));
  auto lp = reinterpret_cast<__attribute__((address_space(3))) char*>(
      reinterpret_cast<uintptr_t>(l));
  __builtin_amdgcn_global_load_lds(gp, lp, 16, 0, 0);
}

__device__ __forceinline__ float blk_sum(float v) {
  __shared__ float sm[4];
  #pragma unroll
  for (int o = 32; o > 0; o >>= 1) v += __shfl_xor(v, o);
  if ((threadIdx.x & 63) == 0) sm[threadIdx.x >> 6] = v;
  __syncthreads();
  float r = sm[0] + sm[1] + sm[2] + sm[3];
  __syncthreads();
  return r;
}

// ---------- small kernels ----------
__global__ __launch_bounds__(256) void k_cvt(const f32x4* __restrict__ in,
                                             u16x8* __restrict__ out) {
  size_t i = (size_t)blockIdx.x * 256 + threadIdx.x;
  f32x4 a = in[i * 2], b = in[i * 2 + 1];
  u16x8 o;
  o[0] = f2b(a[0]); o[1] = f2b(a[1]); o[2] = f2b(a[2]); o[3] = f2b(a[3]);
  o[4] = f2b(b[0]); o[5] = f2b(b[1]); o[6] = f2b(b[2]); o[7] = f2b(b[3]);
  out[i] = o;
}

__global__ __launch_bounds__(256) void k_embed(const int* __restrict__ tok,
                                               const float* __restrict__ emb,
                                               float* __restrict__ x) {
  const int r = blockIdx.x;
  const int tk = tok[r];
  f32x4 v = ((const f32x4*)(emb + (size_t)tk * DIMN))[threadIdx.x];
  float ss = v[0]*v[0] + v[1]*v[1] + v[2]*v[2] + v[3]*v[3];
  float tot = blk_sum(ss);
  float nrm = sqrtf(tot);
  float s = (nrm > 1.f) ? (1.f / (nrm + 1e-7f)) : 1.f;
  f32x4 o = {v[0]*s, v[1]*s, v[2]*s, v[3]*s};
  ((f32x4*)(x + (size_t)r * DIMN))[threadIdx.x] = o;
}

__global__ __launch_bounds__(256) void k_rms(const float* __restrict__ x,
                                             const float* __restrict__ wgt,
                                             u16* __restrict__ out) {
  const int r = blockIdx.x;
  f32x4 v = ((const f32x4*)(x + (size_t)r * DIMN))[threadIdx.x];
  float ss = v[0]*v[0] + v[1]*v[1] + v[2]*v[2] + v[3]*v[3];
  float tot = blk_sum(ss);
  float sc = rsqrtf(tot * (1.f / DIMN) + 1e-6f);
  f32x4 w = ((const f32x4*)wgt)[threadIdx.x];
  u16x4 o;
  o[0] = f2b(v[0] * sc * w[0]);
  o[1] = f2b(v[1] * sc * w[1]);
  o[2] = f2b(v[2] * sc * w[2]);
  o[3] = f2b(v[3] * sc * w[3]);
  ((u16x4*)(out + (size_t)r * DIMN))[threadIdx.x] = o;
}

// scan phase A: per-chunk aggregates (A = prod f, V = chunk-local scan end)
__global__ __launch_bounds__(256) void k_scanA(const float* __restrict__ f,
                                               const float* __restrict__ ti,
                                               const float* __restrict__ gg,
                                               float* __restrict__ Ac,
                                               float* __restrict__ Vc) {
  const int bx = blockIdx.x;              // b*256 + c*4 + dg
  const int dg = bx & 3, c = (bx >> 2) & 63, b = bx >> 8;
  const int d = dg * 256 + threadIdx.x;
  const size_t base = ((size_t)(b * SEQ + c * LCHUNK)) * DIMN + d;
  float a = 1.f, h = 0.f;
  #pragma unroll 4
  for (int t = 0; t < LCHUNK; ++t) {
    size_t ix = base + (size_t)t * DIMN;
    float fv = f[ix];
    float vv = ti[ix] * gg[ix];
    h = fv * h + vv;
    a *= fv;
  }
  const size_t ci = ((size_t)(b * NCHUNK + c)) * DIMN + d;
  Ac[ci] = a; Vc[ci] = h;
}

// scan phase B: exclusive scan over chunks, init = h0
__global__ __launch_bounds__(256) void k_scanB(const float* __restrict__ Ac,
                                               const float* __restrict__ Vc,
                                               const float* __restrict__ h0,
                                               float* __restrict__ carry) {
  const int idx = blockIdx.x * 256 + threadIdx.x;  // 0..2047
  const int b = idx >> 10, d = idx & 1023;
  float h = h0[d];
  for (int c = 0; c < NCHUNK; ++c) {
    size_t ci = ((size_t)(b * NCHUNK + c)) * DIMN + d;
    carry[ci] = h;
    h = Ac[ci] * h + Vc[ci];
  }
}

// scan phase C: recompute with carry-in, y = tanh(h)*sig(og), x += y
__global__ __launch_bounds__(256) void k_scanC(const float* __restrict__ f,
                                               const float* __restrict__ ti,
                                               const float* __restrict__ gg,
                                               const float* __restrict__ oo,
                                               const float* __restrict__ carry,
                                               float* __restrict__ x) {
  const int bx = blockIdx.x;
  const int dg = bx & 3, c = (bx >> 2) & 63, b = bx >> 8;
  const int d = dg * 256 + threadIdx.x;
  const size_t base = ((size_t)(b * SEQ + c * LCHUNK)) * DIMN + d;
  float h = carry[((size_t)(b * NCHUNK + c)) * DIMN + d];
  for (int t = 0; t < LCHUNK; ++t) {
    size_t ix = base + (size_t)t * DIMN;
    float fv = f[ix];
    h = fv * h + ti[ix] * gg[ix];
    float y = ftanh(h) * oo[ix];
    x[ix] += y;
  }
}

// ---------- 128-tile GEMM (m97 structure, proven round 1) ----------
constexpr int EPI_GATES = 0, EPI_SILU_BF = 1, EPI_MUL_BF = 2, EPI_RES_F32 = 3,
              EPI_BIAS_F32 = 4;

template<int BN_T, int EPI>
__global__ __launch_bounds__(256, 2)
void gemm_bt(const u16* __restrict__ A,
             const u16* __restrict__ B0,
             const float* __restrict__ bias0,
             float* __restrict__ oF0,
             u16* __restrict__ oB,
             const u16* __restrict__ exB, const float* __restrict__ exF,
             int N, int K)
{
  constexpr int MF = (BN_T == 128) ? 4 : 2;
  constexpr int WAVES_N = (BN_T == 128) ? 2 : 1;
  constexpr int ISS_B = BN_T / 32;
  __shared__ __align__(16) u16 As[128 * 64];
  __shared__ __align__(16) u16 Bs[BN_T * 64];
  const int tid = threadIdx.x;
  const int w = tid >> 6, lane = tid & 63;
  const int wm = w / WAVES_N, wn = w % WAVES_N;
  const int m0 = blockIdx.x * 128;
  const int n0 = blockIdx.y * BN_T;

  const u16* Bw = B0;
  const float* bias = bias0;
  float* oF = oF0;

  const f32x4 zero = {0.f, 0.f, 0.f, 0.f};
  f32x4 acc[MF][4];
  #pragma unroll
  for (int mf = 0; mf < MF; ++mf)
    #pragma unroll
    for (int nf = 0; nf < 4; ++nf) acc[mf][nf] = zero;

  for (int kt = 0; kt < K; kt += 64) {
    #pragma unroll
    for (int i = 0; i < 4; ++i) {
      int p = i * 4096 + w * 1024 + lane * 16;
      int r = p >> 7;
      int cs = (p & 127) ^ ((r & 7) << 4);
      async16(A + ((size_t)(m0 + r) * K + kt) + (cs >> 1),
              (char*)As + i * 4096 + w * 1024);
    }
    #pragma unroll
    for (int i = 0; i < ISS_B; ++i) {
      int p = i * 4096 + w * 1024 + lane * 16;
      int r = p >> 7;
      int cs = (p & 127) ^ ((r & 7) << 4);
      async16(Bw + ((size_t)(n0 + r) * K + kt) + (cs >> 1),
              (char*)Bs + i * 4096 + w * 1024);
    }
    __syncthreads();
    #pragma unroll
    for (int ks = 0; ks < 2; ++ks) {
      bf16x8 av[MF], bv[4];
      const int cbase = ks * 64 + ((lane >> 4) << 4);
      #pragma unroll
      for (int mf = 0; mf < MF; ++mf) {
        int r = wm * (MF * 16) + mf * 16 + (lane & 15);
        av[mf] = *(const bf16x8*)((const char*)As + r * 128 + (cbase ^ ((r & 7) << 4)));
      }
      #pragma unroll
      for (int nf = 0; nf < 4; ++nf) {
        int r = wn * 64 + nf * 16 + (lane & 15);
        bv[nf] = *(const bf16x8*)((const char*)Bs + r * 128 + (cbase ^ ((r & 7) << 4)));
      }
      #pragma unroll
      for (int mf = 0; mf < MF; ++mf)
        #pragma unroll
        for (int nf = 0; nf < 4; ++nf)
          acc[mf][nf] = __builtin_amdgcn_mfma_f32_16x16x32_bf16(
              av[mf], bv[nf], acc[mf][nf], 0, 0, 0);
    }
    __syncthreads();
  }

  #pragma unroll
  for (int nf = 0; nf < 4; ++nf) {
    const int n = n0 + wn * 64 + nf * 16 + (lane & 15);
    const float bb = bias[n];
    #pragma unroll
    for (int mf = 0; mf < MF; ++mf) {
      #pragma unroll
      for (int j = 0; j < 4; ++j) {
        const int m = m0 + wm * (MF * 16) + mf * 16 + ((lane >> 4) << 2) + j;
        const size_t idx = (size_t)m * N + n;
        float v = acc[mf][nf][j] + bb;
        if constexpr (EPI == EPI_SILU_BF) {
          oB[idx] = f2b(v * sigm(v));
        } else if constexpr (EPI == EPI_MUL_BF) {
          oB[idx] = f2b(v * b2f(exB[idx]));
        } else if constexpr (EPI == EPI_RES_F32) {
          oF[idx] = v + exF[idx];
        } else {
          oF[idx] = v;
        }
      }
    }
  }
}

// ---------- 256-tile 4-phase GEMM, bucketed staging + counted vmcnt ----------
// C = A[M,K] @ B[N,K]^T. 512 thr = 8 waves (2M x 4N); per-wave 128x64 out.
// LDS: 2 bufs x (A 32KB + B 32KB) = 128KB. Per K-tile: 8 issues/wave in 3
// buckets ordered by consumption phase:
//   b0 (4/wave, issued ph0 of prev tile): A rows 0-63,128-191 + B rows (r&63)<32
//   b1 (2/wave, issued ph1):              B rows (r&63)>=32
//   b2 (2/wave, issued ph2):              A rows 64-127,192-255
// Waits: vmcnt(6) end-ph0 (gates b1, issued 4 phases back), vmcnt(6) end-ph1
// (gates b2), vmcnt(4) at tile boundary (gates next b0). Never 0 mid-loop.
constexpr int EG4 = 0, ESILU = 1, EMUL = 2, EVOC = 3;

template<int EPI>
__global__ __launch_bounds__(512, 2)
void gemm256(const u16* __restrict__ A, const u16* __restrict__ Bm,
             const float* __restrict__ b0, const float* __restrict__ b1,
             const float* __restrict__ b2, const float* __restrict__ b3,
             float* __restrict__ f0, float* __restrict__ f1,
             float* __restrict__ f2, float* __restrict__ f3,
             u16* __restrict__ oB, const u16* __restrict__ exB,
             float* __restrict__ oF,
             int N, int K, int GX)
{
  __shared__ __align__(16) char lds[131072];
  const int tid = threadIdx.x;
  const int w = tid >> 6, lane = tid & 63;
  const int wm = w >> 2, wn = w & 3;
  // XCD-aware swizzle (all grids here are %8==0)
  const int nwg = gridDim.x, bid = blockIdx.x;
  const int swz = (bid & 7) * (nwg >> 3) + (bid >> 3);
  const int m0 = (swz % GX) * 256;
  const int n0 = (swz / GX) * 256;

  // bucketed staging plan: LDS byte (within 64KB buf) of this wave's 8 issues
  int Dj[8];
  #pragma unroll
  for (int j = 0; j < 2; ++j) {          // b0: A groups {0-7,16-23}
    const int idx = w * 2 + j;
    const int ga = (idx < 8) ? idx : idx + 8;
    Dj[j] = ga << 10;
  }
  #pragma unroll
  for (int j = 0; j < 2; ++j) {          // b0: B groups (g&7)<4
    const int idx = w * 2 + j;
    const int gb = ((idx >> 2) << 3) + (idx & 3);
    Dj[2 + j] = 32768 + (gb << 10);
  }
  #pragma unroll
  for (int j = 0; j < 2; ++j) {          // b1: B groups (g&7)>=4
    const int idx = w * 2 + j;
    const int gb = ((idx >> 2) << 3) + 4 + (idx & 3);
    Dj[4 + j] = 32768 + (gb << 10);
  }
  #pragma unroll
  for (int j = 0; j < 2; ++j) {          // b2: A groups {8-15,24-31}
    const int idx = w * 2 + j;
    const int ga = (idx < 8) ? (8 + idx) : (16 + idx);
    Dj[6 + j] = ga << 10;
  }

  auto issue = [&](int buf, int j, int kt) {
    const int d = Dj[j];
    const int qq = d + (lane << 4);
    const int row = (qq & 32767) >> 7;           // tile-local row 0..255
    const int cs = (qq & 127) ^ ((row & 7) << 4);
    const u16* src = (qq >> 15)
        ? (Bm + ((size_t)(n0 + row) * K + kt) + (cs >> 1))
        : (A  + ((size_t)(m0 + row) * K + kt) + (cs >> 1));
    async16(src, lds + (buf << 16) + d);
  };
  auto rdA = [&](int buf, int mf, int ks) -> bf16x8 {
    const int row = wm * 128 + mf * 16 + (lane & 15);
    const int col = (ks * 64 + ((lane >> 4) << 4)) ^ ((row & 7) << 4);
    return *(const bf16x8*)(lds + (buf << 16) + row * 128 + col);
  };
  auto rdB = [&](int buf, int nf, int ks) -> bf16x8 {
    const int row = wn * 64 + nf * 16 + (lane & 15);
    const int col = (ks * 64 + ((lane >> 4) << 4)) ^ ((row & 7) << 4);
    return *(const bf16x8*)(lds + (buf << 16) + 32768 + row * 128 + col);
  };

  const f32x4 zero = {0.f, 0.f, 0.f, 0.f};
  f32x4 acc[8][4];
  #pragma unroll
  for (int mf = 0; mf < 8; ++mf)
    #pragma unroll
    for (int nf = 0; nf < 4; ++nf) acc[mf][nf] = zero;
  bf16x8 av[4][2], bv[2][2];

#define MM256(MFO, NFO)                                                    \
  __builtin_amdgcn_s_setprio(1);                                           \
  _Pragma("unroll")                                                        \
  for (int mf = 0; mf < 4; ++mf)                                           \
    _Pragma("unroll")                                                      \
    for (int nf = 0; nf < 2; ++nf)                                         \
      _Pragma("unroll")                                                    \
      for (int ks = 0; ks < 2; ++ks)                                       \
        acc[(MFO) + mf][(NFO) + nf] = __builtin_amdgcn_mfma_f32_16x16x32_bf16( \
            av[mf][ks], bv[nf][ks], acc[(MFO) + mf][(NFO) + nf], 0, 0, 0); \
  __builtin_amdgcn_s_setprio(0);

  const int NT = K >> 6;
  // prologue: stage all buckets of tile 0; gate b0 only
  #pragma unroll
  for (int j = 0; j < 8; ++j) issue(0, j, 0);
  asm volatile("s_waitcnt vmcnt(4)" ::: "memory");
  __builtin_amdgcn_s_barrier();

  for (int t = 0; t < NT; ++t) {
    const int buf = t & 1, nbuf = buf ^ 1;
    const bool pf = (t + 1 < NT);
    const int kn = (t + 1) << 6;

    // ---- phase 0: A mf0-3 + B nf0-1 (bucket0) ----
    #pragma unroll
    for (int mf = 0; mf < 4; ++mf) { av[mf][0] = rdA(buf, mf, 0); av[mf][1] = rdA(buf, mf, 1); }
    #pragma unroll
    for (int nf = 0; nf < 2; ++nf) { bv[nf][0] = rdB(buf, nf, 0); bv[nf][1] = rdB(buf, nf, 1); }
    if (pf) { issue(nbuf, 0, kn); issue(nbuf, 1, kn); issue(nbuf, 2, kn); issue(nbuf, 3, kn); }
    __builtin_amdgcn_s_barrier();
    asm volatile("s_waitcnt lgkmcnt(0)" ::: "memory");
    MM256(0, 0)
    if (pf) asm volatile("s_waitcnt vmcnt(6)" ::: "memory");  // b1(t) landed
    else    asm volatile("s_waitcnt vmcnt(2)" ::: "memory");
    __builtin_amdgcn_s_barrier();

    // ---- phase 1: B nf2-3 (bucket1) ----
    #pragma unroll
    for (int nf = 0; nf < 2; ++nf) { bv[nf][0] = rdB(buf, 2 + nf, 0); bv[nf][1] = rdB(buf, 2 + nf, 1); }
    if (pf) { issue(nbuf, 4, kn); issue(nbuf, 5, kn); }
    __builtin_amdgcn_s_barrier();
    asm volatile("s_waitcnt lgkmcnt(0)" ::: "memory");
    MM256(0, 2)
    if (pf) asm volatile("s_waitcnt vmcnt(6)" ::: "memory");  // b2(t) landed
    else    asm volatile("s_waitcnt vmcnt(0)" ::: "memory");
    __builtin_amdgcn_s_barrier();

    // ---- phase 2: A mf4-7 (bucket2) ----
    #pragma unroll
    for (int mf = 0; mf < 4; ++mf) { av[mf][0] = rdA(buf, 4 + mf, 0); av[mf][1] = rdA(buf, 4 + mf, 1); }
    if (pf) { issue(nbuf, 6, kn); issue(nbuf, 7, kn); }
    __builtin_amdgcn_s_barrier();
    asm volatile("s_waitcnt lgkmcnt(0)" ::: "memory");
    MM256(4, 2)
    __builtin_amdgcn_s_barrier();

    // ---- phase 3: B nf0-1 again (resident bucket0) ----
    #pragma unroll
    for (int nf = 0; nf < 2; ++nf) { bv[nf][0] = rdB(buf, nf, 0); bv[nf][1] = rdB(buf, nf, 1); }
    __builtin_amdgcn_s_barrier();
    asm volatile("s_waitcnt lgkmcnt(0)" ::: "memory");
    MM256(4, 0)
    if (pf) asm volatile("s_waitcnt vmcnt(4)" ::: "memory");  // b0(t+1) landed
    __builtin_amdgcn_s_barrier();
  }
#undef MM256

  // epilogue: C/D map col=lane&15, row=(lane>>4)*4+j
  if constexpr (EPI == EG4) {
    const int z = n0 >> 10;  // uniform per block
    const float* bz = (z == 0) ? b0 : (z == 1) ? b1 : (z == 2) ? b2 : b3;
    float* fz = (z == 0) ? f0 : (z == 1) ? f1 : (z == 2) ? f2 : f3;
    #pragma unroll
    for (int nf = 0; nf < 4; ++nf) {
      const int n = (n0 & 1023) + wn * 64 + nf * 16 + (lane & 15);
      const float bb = bz[n];
      #pragma unroll
      for (int mf = 0; mf < 8; ++mf)
        #pragma unroll
        for (int j = 0; j < 4; ++j) {
          const int m = m0 + wm * 128 + mf * 16 + ((lane >> 4) << 2) + j;
          float v = acc[mf][nf][j] + bb;
          fz[(size_t)m * 1024 + n] = (z == 1) ? ftanh(v) : sigm(v);
        }
    }
  } else {
    #pragma unroll
    for (int nf = 0; nf < 4; ++nf) {
      const int n = n0 + wn * 64 + nf * 16 + (lane & 15);
      const float bb = b0[n];
      #pragma unroll
      for (int mf = 0; mf < 8; ++mf)
        #pragma unroll
        for (int j = 0; j < 4; ++j) {
          const int m = m0 + wm * 128 + mf * 16 + ((lane >> 4) << 2) + j;
          const size_t idx = (size_t)m * N + n;
          float v = acc[mf][nf][j] + bb;
          if constexpr (EPI == ESILU) {
            oB[idx] = f2b(v * sigm(v));
          } else if constexpr (EPI == EMUL) {
            oB[idx] = f2b(v * b2f(exB[idx]));
          } else {
            oF[idx] = v;
          }
        }
    }
  }
}

// ---------- launcher ----------
extern "C" void kernel_launch(void* const* d_in, const int* in_sizes, int n_in,
                              void* d_out, int out_size, void* d_ws, size_t ws_size,
                              hipStream_t stream) {
  (void)in_sizes; (void)n_in; (void)out_size; (void)ws_size;
  const int*   tokens = (const int*)d_in[0];
  const float* emb  = (const float*)d_in[1];
  const float* h0   = (const float*)d_in[2];
  const float* Wf   = (const float*)d_in[3];
  const float* bf_  = (const float*)d_in[4];
  const float* Wi   = (const float*)d_in[5];
  const float* bi_  = (const float*)d_in[6];
  const float* Wig  = (const float*)d_in[7];
  const float* big_ = (const float*)d_in[8];
  const float* Wog  = (const float*)d_in[9];
  const float* bog_ = (const float*)d_in[10];
  const float* n1   = (const float*)d_in[11];
  const float* n2   = (const float*)d_in[12];
  const float* Wfc  = (const float*)d_in[13];
  const float* bfc_ = (const float*)d_in[14];
  const float* Wfa  = (const float*)d_in[15];
  const float* bfa_ = (const float*)d_in[16];
  const float* Wfo  = (const float*)d_in[17];
  const float* bfo_ = (const float*)d_in[18];
  const float* nl_  = (const float*)d_in[19];
  const float* Wout = (const float*)d_in[20];
  const float* bout_= (const float*)d_in[21];
  float* out = (float*)d_out;

  char* p = (char*)d_ws;
  auto alloc = [&](size_t bytes) {
    char* r = p; p += (bytes + 255) & ~(size_t)255; return r;
  };
  u16* wbGates = (u16*)alloc((size_t)4 * DIMN * DIMN * 2);  // [4*1024,1024]
  u16* wbWfc  = (u16*)alloc((size_t)FFD * DIMN * 2);
  u16* wbWfa  = (u16*)alloc((size_t)FFD * DIMN * 2);
  u16* wbWfo  = (u16*)alloc((size_t)FFD * DIMN * 2);
  u16* wbWout = (u16*)alloc((size_t)VOCAB * DIMN * 2);
  float* x    = (float*)alloc((size_t)MROWS * DIMN * 4);
  u16* hin    = (u16*)alloc((size_t)MROWS * DIMN * 2);
  float* fbuf = (float*)alloc((size_t)MROWS * DIMN * 4);
  float* tibuf= (float*)alloc((size_t)MROWS * DIMN * 4);
  float* ggbuf= (float*)alloc((size_t)MROWS * DIMN * 4);
  float* oobuf= (float*)alloc((size_t)MROWS * DIMN * 4);
  // FFN intermediates alias the (then-dead) gate buffers:
  u16* sa = (u16*)fbuf;                                   // [4096,4096] bf16
  u16* ub = (u16*)((char*)fbuf + (size_t)MROWS * FFD * 2);// [4096,4096] bf16
  float* Ac    = (float*)alloc((size_t)2 * NCHUNK * DIMN * 4);
  float* Vc    = (float*)alloc((size_t)2 * NCHUNK * DIMN * 4);
  float* carry = (float*)alloc((size_t)2 * NCHUNK * DIMN * 4);

  auto cvt = [&](const float* src, u16* dst, size_t nelem) {
    k_cvt<<<dim3((unsigned)(nelem / 2048)), dim3(256), 0, stream>>>(
        (const f32x4*)src, (u16x8*)dst);
  };

  k_embed<<<dim3(MROWS), dim3(256), 0, stream>>>(tokens, emb, x);

  for (int L = 0; L < D_LAYERS; ++L) {
    const size_t oDD = (size_t)L * DIMN * DIMN;
    const size_t oFD = (size_t)L * FFD * DIMN;
    cvt(Wf  + oDD, wbGates + (size_t)0 * DIMN * DIMN, (size_t)DIMN * DIMN);
    cvt(Wi  + oDD, wbGates + (size_t)1 * DIMN * DIMN, (size_t)DIMN * DIMN);
    cvt(Wig + oDD, wbGates + (size_t)2 * DIMN * DIMN, (size_t)DIMN * DIMN);
    cvt(Wog + oDD, wbGates + (size_t)3 * DIMN * DIMN, (size_t)DIMN * DIMN);
    cvt(Wfc + oFD, wbWfc, (size_t)FFD * DIMN);
    cvt(Wfa + oFD, wbWfa, (size_t)FFD * DIMN);
    cvt(Wfo + oFD, wbWfo, (size_t)FFD * DIMN);

    k_rms<<<dim3(MROWS), dim3(256), 0, stream>>>(x, n1 + (size_t)L * DIMN, hin);

    // fused 4-gate GEMM: [4096,1024] @ [4096,1024]^T, route by n>>10
    gemm256<EG4><<<dim3(256), dim3(512), 0, stream>>>(
        hin, wbGates,
        bf_ + (size_t)L * DIMN, bi_ + (size_t)L * DIMN,
        big_ + (size_t)L * DIMN, bog_ + (size_t)L * DIMN,
        fbuf, tibuf, ggbuf, oobuf,
        nullptr, nullptr, nullptr, 4096, DIMN, 16);

    k_scanA<<<dim3(512), dim3(256), 0, stream>>>(fbuf, tibuf, ggbuf, Ac, Vc);
    k_scanB<<<dim3(8), dim3(256), 0, stream>>>(Ac, Vc, h0 + (size_t)L * DIMN, carry);
    k_scanC<<<dim3(512), dim3(256), 0, stream>>>(fbuf, tibuf, ggbuf, oobuf, carry, x);

    k_rms<<<dim3(MROWS), dim3(256), 0, stream>>>(x, n2 + (size_t)L * DIMN, hin);

    gemm256<ESILU><<<dim3(256), dim3(512), 0, stream>>>(
        hin, wbWfa,
        bfa_ + (size_t)L * FFD, nullptr, nullptr, nullptr,
        nullptr, nullptr, nullptr, nullptr,
        sa, nullptr, nullptr, FFD, DIMN, 16);

    gemm256<EMUL><<<dim3(256), dim3(512), 0, stream>>>(
        hin, wbWfc,
        bfc_ + (size_t)L * FFD, nullptr, nullptr, nullptr,
        nullptr, nullptr, nullptr, nullptr,
        ub, sa, nullptr, FFD, DIMN, 16);

    gemm_bt<64, EPI_RES_F32><<<dim3(32, 16), dim3(256), 0, stream>>>(
        ub, wbWfo,
        bfo_ + (size_t)L * DIMN,
        x, nullptr, nullptr, x, DIMN, FFD);
  }

  cvt(Wout, wbWout, (size_t)VOCAB * DIMN);
  k_rms<<<dim3(MROWS), dim3(256), 0, stream>>>(x, nl_, hin);
  gemm256<EVOC><<<dim3(2000), dim3(512), 0, stream>>>(
      hin, wbWout,
      bout_, nullptr, nullptr, nullptr,
      nullptr, nullptr, nullptr, nullptr,
      nullptr, nullptr, out, VOCAB, DIMN, 16);
}

// Round 5
// 2719.479 us; speedup vs baseline: 1.0935x; 1.0069x over previous
//
#include <hip/hip_runtime.h>
#include <hip/hip_bf16.h>
#include <cstdint>
#include <cstddef>

typedef unsigned short u16;
typedef __attribute__((ext_vector_type(4))) float f32x4;
typedef __attribute__((ext_vector_type(8))) short bf16x8;
typedef __attribute__((ext_vector_type(8))) unsigned short u16x8;
typedef __attribute__((ext_vector_type(4))) unsigned short u16x4;

#define D_LAYERS 8
#define DIMN 1024
#define FFD 4096
#define VOCAB 32000
#define MROWS 4096   /* B*S */
#define SEQ 2048
#define NCHUNK 64
#define LCHUNK 32

// ---------- helpers ----------
__device__ __forceinline__ u16 f2b(float f) {
  union { float f; unsigned u; } v; v.f = f;
  unsigned r = v.u + 0x7FFFu + ((v.u >> 16) & 1u);
  return (u16)(r >> 16);
}
__device__ __forceinline__ float b2f(u16 h) {
  union { unsigned u; float f; } v; v.u = ((unsigned)h) << 16;
  return v.f;
}
__device__ __forceinline__ float sigm(float x) { return 1.f / (1.f + __expf(-x)); }
__device__ __forceinline__ float ftanh(float x) {
  float e = __expf(2.f * x);
  return 1.f - 2.f / (e + 1.f);
}

// async global->LDS, 16B per lane. LDS dest is wave-uniform base + lane*16 (HW).
__device__ __forceinline__ void async16(const void* g, void* l) {
  auto gp = reinterpret_cast<const __attribute__((address_space(1))) char*>(
      reinterpret_cast<uintptr_t>(g));
  auto lp = reinterpret_cast<__attribute__((address_space(3))) char*>(
      reinterpret_cast<uintptr_t>(l));
  __builtin_amdgcn_global_load_lds(gp, lp, 16, 0, 0);
}

__device__ __forceinline__ float blk_sum(float v) {
  __shared__ float sm[4];
  #pragma unroll
  for (int o = 32; o > 0; o >>= 1) v += __shfl_xor(v, o);
  if ((threadIdx.x & 63) == 0) sm[threadIdx.x >> 6] = v;
  __syncthreads();
  float r = sm[0] + sm[1] + sm[2] + sm[3];
  __syncthreads();
  return r;
}

// ---------- small kernels ----------
__global__ __launch_bounds__(256) void k_cvt(const f32x4* __restrict__ in,
                                             u16x8* __restrict__ out) {
  size_t i = (size_t)blockIdx.x * 256 + threadIdx.x;
  f32x4 a = in[i * 2], b = in[i * 2 + 1];
  u16x8 o;
  o[0] = f2b(a[0]); o[1] = f2b(a[1]); o[2] = f2b(a[2]); o[3] = f2b(a[3]);
  o[4] = f2b(b[0]); o[5] = f2b(b[1]); o[6] = f2b(b[2]); o[7] = f2b(b[3]);
  out[i] = o;
}

__global__ __launch_bounds__(256) void k_embed(const int* __restrict__ tok,
                                               const float* __restrict__ emb,
                                               float* __restrict__ x) {
  const int r = blockIdx.x;
  const int tk = tok[r];
  f32x4 v = ((const f32x4*)(emb + (size_t)tk * DIMN))[threadIdx.x];
  float ss = v[0]*v[0] + v[1]*v[1] + v[2]*v[2] + v[3]*v[3];
  float tot = blk_sum(ss);
  float nrm = sqrtf(tot);
  float s = (nrm > 1.f) ? (1.f / (nrm + 1e-7f)) : 1.f;
  f32x4 o = {v[0]*s, v[1]*s, v[2]*s, v[3]*s};
  ((f32x4*)(x + (size_t)r * DIMN))[threadIdx.x] = o;
}

__global__ __launch_bounds__(256) void k_rms(const float* __restrict__ x,
                                             const float* __restrict__ wgt,
                                             u16* __restrict__ out) {
  const int r = blockIdx.x;
  f32x4 v = ((const f32x4*)(x + (size_t)r * DIMN))[threadIdx.x];
  float ss = v[0]*v[0] + v[1]*v[1] + v[2]*v[2] + v[3]*v[3];
  float tot = blk_sum(ss);
  float sc = rsqrtf(tot * (1.f / DIMN) + 1e-6f);
  f32x4 w = ((const f32x4*)wgt)[threadIdx.x];
  u16x4 o;
  o[0] = f2b(v[0] * sc * w[0]);
  o[1] = f2b(v[1] * sc * w[1]);
  o[2] = f2b(v[2] * sc * w[2]);
  o[3] = f2b(v[3] * sc * w[3]);
  ((u16x4*)(out + (size_t)r * DIMN))[threadIdx.x] = o;
}

// scan phase A: per-chunk aggregates (A = prod f, V = chunk-local scan end)
__global__ __launch_bounds__(256) void k_scanA(const float* __restrict__ f,
                                               const float* __restrict__ ti,
                                               const float* __restrict__ gg,
                                               float* __restrict__ Ac,
                                               float* __restrict__ Vc) {
  const int bx = blockIdx.x;              // b*256 + c*4 + dg
  const int dg = bx & 3, c = (bx >> 2) & 63, b = bx >> 8;
  const int d = dg * 256 + threadIdx.x;
  const size_t base = ((size_t)(b * SEQ + c * LCHUNK)) * DIMN + d;
  float a = 1.f, h = 0.f;
  #pragma unroll 4
  for (int t = 0; t < LCHUNK; ++t) {
    size_t ix = base + (size_t)t * DIMN;
    float fv = f[ix];
    float vv = ti[ix] * gg[ix];
    h = fv * h + vv;
    a *= fv;
  }
  const size_t ci = ((size_t)(b * NCHUNK + c)) * DIMN + d;
  Ac[ci] = a; Vc[ci] = h;
}

// scan phase B: exclusive scan over chunks, init = h0
__global__ __launch_bounds__(256) void k_scanB(const float* __restrict__ Ac,
                                               const float* __restrict__ Vc,
                                               const float* __restrict__ h0,
                                               float* __restrict__ carry) {
  const int idx = blockIdx.x * 256 + threadIdx.x;  // 0..2047
  const int b = idx >> 10, d = idx & 1023;
  float h = h0[d];
  for (int c = 0; c < NCHUNK; ++c) {
    size_t ci = ((size_t)(b * NCHUNK + c)) * DIMN + d;
    carry[ci] = h;
    h = Ac[ci] * h + Vc[ci];
  }
}

// scan phase C: recompute with carry-in, y = tanh(h)*sig(og), x += y
__global__ __launch_bounds__(256) void k_scanC(const float* __restrict__ f,
                                               const float* __restrict__ ti,
                                               const float* __restrict__ gg,
                                               const float* __restrict__ oo,
                                               const float* __restrict__ carry,
                                               float* __restrict__ x) {
  const int bx = blockIdx.x;
  const int dg = bx & 3, c = (bx >> 2) & 63, b = bx >> 8;
  const int d = dg * 256 + threadIdx.x;
  const size_t base = ((size_t)(b * SEQ + c * LCHUNK)) * DIMN + d;
  float h = carry[((size_t)(b * NCHUNK + c)) * DIMN + d];
  for (int t = 0; t < LCHUNK; ++t) {
    size_t ix = base + (size_t)t * DIMN;
    float fv = f[ix];
    h = fv * h + ti[ix] * gg[ix];
    float y = ftanh(h) * oo[ix];
    x[ix] += y;
  }
}

// ---------- 128-tile GEMM (m97 structure, proven round 1) ----------
constexpr int EPI_GATES = 0, EPI_SILU_BF = 1, EPI_MUL_BF = 2, EPI_RES_F32 = 3,
              EPI_BIAS_F32 = 4;

template<int BN_T, int EPI>
__global__ __launch_bounds__(256, 2)
void gemm_bt(const u16* __restrict__ A,
             const u16* __restrict__ B0,
             const float* __restrict__ bias0,
             float* __restrict__ oF0,
             u16* __restrict__ oB,
             const u16* __restrict__ exB, const float* __restrict__ exF,
             int N, int K)
{
  constexpr int MF = (BN_T == 128) ? 4 : 2;
  constexpr int WAVES_N = (BN_T == 128) ? 2 : 1;
  constexpr int ISS_B = BN_T / 32;
  __shared__ __align__(16) u16 As[128 * 64];
  __shared__ __align__(16) u16 Bs[BN_T * 64];
  const int tid = threadIdx.x;
  const int w = tid >> 6, lane = tid & 63;
  const int wm = w / WAVES_N, wn = w % WAVES_N;
  const int m0 = blockIdx.x * 128;
  const int n0 = blockIdx.y * BN_T;

  const u16* Bw = B0;
  const float* bias = bias0;
  float* oF = oF0;

  const f32x4 zero = {0.f, 0.f, 0.f, 0.f};
  f32x4 acc[MF][4];
  #pragma unroll
  for (int mf = 0; mf < MF; ++mf)
    #pragma unroll
    for (int nf = 0; nf < 4; ++nf) acc[mf][nf] = zero;

  for (int kt = 0; kt < K; kt += 64) {
    #pragma unroll
    for (int i = 0; i < 4; ++i) {
      int p = i * 4096 + w * 1024 + lane * 16;
      int r = p >> 7;
      int cs = (p & 127) ^ ((r & 7) << 4);
      async16(A + ((size_t)(m0 + r) * K + kt) + (cs >> 1),
              (char*)As + i * 4096 + w * 1024);
    }
    #pragma unroll
    for (int i = 0; i < ISS_B; ++i) {
      int p = i * 4096 + w * 1024 + lane * 16;
      int r = p >> 7;
      int cs = (p & 127) ^ ((r & 7) << 4);
      async16(Bw + ((size_t)(n0 + r) * K + kt) + (cs >> 1),
              (char*)Bs + i * 4096 + w * 1024);
    }
    __syncthreads();
    #pragma unroll
    for (int ks = 0; ks < 2; ++ks) {
      bf16x8 av[MF], bv[4];
      const int cbase = ks * 64 + ((lane >> 4) << 4);
      #pragma unroll
      for (int mf = 0; mf < MF; ++mf) {
        int r = wm * (MF * 16) + mf * 16 + (lane & 15);
        av[mf] = *(const bf16x8*)((const char*)As + r * 128 + (cbase ^ ((r & 7) << 4)));
      }
      #pragma unroll
      for (int nf = 0; nf < 4; ++nf) {
        int r = wn * 64 + nf * 16 + (lane & 15);
        bv[nf] = *(const bf16x8*)((const char*)Bs + r * 128 + (cbase ^ ((r & 7) << 4)));
      }
      #pragma unroll
      for (int mf = 0; mf < MF; ++mf)
        #pragma unroll
        for (int nf = 0; nf < 4; ++nf)
          acc[mf][nf] = __builtin_amdgcn_mfma_f32_16x16x32_bf16(
              av[mf], bv[nf], acc[mf][nf], 0, 0, 0);
    }
    __syncthreads();
  }

  #pragma unroll
  for (int nf = 0; nf < 4; ++nf) {
    const int n = n0 + wn * 64 + nf * 16 + (lane & 15);
    const float bb = bias[n];
    #pragma unroll
    for (int mf = 0; mf < MF; ++mf) {
      #pragma unroll
      for (int j = 0; j < 4; ++j) {
        const int m = m0 + wm * (MF * 16) + mf * 16 + ((lane >> 4) << 2) + j;
        const size_t idx = (size_t)m * N + n;
        float v = acc[mf][nf][j] + bb;
        if constexpr (EPI == EPI_SILU_BF) {
          oB[idx] = f2b(v * sigm(v));
        } else if constexpr (EPI == EPI_MUL_BF) {
          oB[idx] = f2b(v * b2f(exB[idx]));
        } else if constexpr (EPI == EPI_RES_F32) {
          oF[idx] = v + exF[idx];
        } else {
          oF[idx] = v;
        }
      }
    }
  }
}

// ---------- 256-tile GEMM v2fix: 1 barrier + 1 vmcnt per K-tile ----------
// C = A[M,K] @ B[N,K]^T. 512 thr = 8 waves (2M x 4N); per-wave 128x64 out.
// LDS: 2 bufs x (A 32KB + B 32KB). Per tile: batch-8 stage for t+1 at P0;
// quadrant MFMAs with operand reads one quadrant ahead (compiler emits
// fine-grained lgkmcnt); ONE {vmcnt(0); s_barrier} per tile at end-P2,
// pinned with sched_barrier(0) both sides (no read may slide between my
// vmcnt and the barrier, rule #18 family). P3: QMM(avHI,bv0) FIRST, then
// next-tile avLO/bv0 reads (round-4 bug: reads clobbered bv0 pre-QMM).
constexpr int EG4 = 0, ESILU = 1, EMUL = 2, EVOC = 3;

template<int EPI>
__global__ __launch_bounds__(512, 2)
void gemm256(const u16* __restrict__ A, const u16* __restrict__ Bm,
             const float* __restrict__ b0, const float* __restrict__ b1,
             const float* __restrict__ b2, const float* __restrict__ b3,
             float* __restrict__ f0, float* __restrict__ f1,
             float* __restrict__ f2, float* __restrict__ f3,
             u16* __restrict__ oB, const u16* __restrict__ exB,
             float* __restrict__ oF,
             int N, int K, int GX)
{
  __shared__ __align__(16) char lds[131072];
  const int tid = threadIdx.x;
  const int w = tid >> 6, lane = tid & 63;
  const int wm = w >> 2, wn = w & 3;
  // XCD-aware swizzle (all grids here are %8==0)
  const int nwg = gridDim.x, bid = blockIdx.x;
  const int swz = (bid & 7) * (nwg >> 3) + (bid >> 3);
  const int m0 = (swz % GX) * 256;
  const int n0 = (swz / GX) * 256;

  auto issue = [&](int buf, int j, int kt) {
    // wave w owns 1KB groups: j0-3 -> A groups w*4+j; j4-7 -> B groups w*4+j-4
    const int d = (j < 4) ? ((w * 4 + j) << 10) : (32768 + ((w * 4 + j - 4) << 10));
    const int qq = d + (lane << 4);
    const int row = (qq & 32767) >> 7;           // tile-local row 0..255
    const int cs = (qq & 127) ^ ((row & 7) << 4);
    const u16* src = (qq >> 15)
        ? (Bm + ((size_t)(n0 + row) * K + kt) + (cs >> 1))
        : (A  + ((size_t)(m0 + row) * K + kt) + (cs >> 1));
    async16(src, lds + (buf << 16) + d);
  };
  auto rdA = [&](int buf, int mf, int ks) -> bf16x8 {
    const int row = wm * 128 + mf * 16 + (lane & 15);
    const int col = (ks * 64 + ((lane >> 4) << 4)) ^ ((row & 7) << 4);
    return *(const bf16x8*)(lds + (buf << 16) + row * 128 + col);
  };
  auto rdB = [&](int buf, int nf, int ks) -> bf16x8 {
    const int row = wn * 64 + nf * 16 + (lane & 15);
    const int col = (ks * 64 + ((lane >> 4) << 4)) ^ ((row & 7) << 4);
    return *(const bf16x8*)(lds + (buf << 16) + 32768 + row * 128 + col);
  };

  const f32x4 zero = {0.f, 0.f, 0.f, 0.f};
  f32x4 acc[8][4];
  #pragma unroll
  for (int mf = 0; mf < 8; ++mf)
    #pragma unroll
    for (int nf = 0; nf < 4; ++nf) acc[mf][nf] = zero;
  bf16x8 avLO[4][2], avHI[4][2], bv0[2][2], bv1[2][2];

// one quadrant: 4mf x 2nf x 2ks = 16 MFMA
#define QMM(AV, BV, MFO, NFO)                                              \
  __builtin_amdgcn_s_setprio(1);                                           \
  _Pragma("unroll")                                                        \
  for (int mf = 0; mf < 4; ++mf)                                           \
    _Pragma("unroll")                                                      \
    for (int nf = 0; nf < 2; ++nf)                                         \
      _Pragma("unroll")                                                    \
      for (int ks = 0; ks < 2; ++ks)                                       \
        acc[(MFO) + mf][(NFO) + nf] = __builtin_amdgcn_mfma_f32_16x16x32_bf16( \
            AV[mf][ks], BV[nf][ks], acc[(MFO) + mf][(NFO) + nf], 0, 0, 0); \
  __builtin_amdgcn_s_setprio(0);

  const int NT = K >> 6;
  // prologue: stage tile 0 -> buf0; sync; read first-quadrant frags
  #pragma unroll
  for (int j = 0; j < 8; ++j) issue(0, j, 0);
  __builtin_amdgcn_sched_barrier(0);
  asm volatile("s_waitcnt vmcnt(0)" ::: "memory");
  __builtin_amdgcn_s_barrier();
  __builtin_amdgcn_sched_barrier(0);
  #pragma unroll
  for (int mf = 0; mf < 4; ++mf) { avLO[mf][0] = rdA(0, mf, 0); avLO[mf][1] = rdA(0, mf, 1); }
  #pragma unroll
  for (int nf = 0; nf < 2; ++nf) { bv0[nf][0] = rdB(0, nf, 0); bv0[nf][1] = rdB(0, nf, 1); }

  for (int t = 0; t < NT; ++t) {
    const int buf = t & 1, nb = buf ^ 1;
    const bool pf = (t + 1 < NT);
    const int kn = (t + 1) << 6;

    // P0: stage batch for t+1; read bv1(buf); MFMA Q(avLO, bv0)
    if (pf) {
      #pragma unroll
      for (int j = 0; j < 8; ++j) issue(nb, j, kn);
    }
    #pragma unroll
    for (int nf = 0; nf < 2; ++nf) { bv1[nf][0] = rdB(buf, 2 + nf, 0); bv1[nf][1] = rdB(buf, 2 + nf, 1); }
    QMM(avLO, bv0, 0, 0)

    // P1: read avHI(buf); MFMA Q(avLO, bv1)
    #pragma unroll
    for (int mf = 0; mf < 4; ++mf) { avHI[mf][0] = rdA(buf, 4 + mf, 0); avHI[mf][1] = rdA(buf, 4 + mf, 1); }
    QMM(avLO, bv1, 0, 2)

    // P2: MFMA Q(avHI, bv1); the tile's single sync point (pinned)
    QMM(avHI, bv1, 4, 2)
    __builtin_amdgcn_sched_barrier(0);
    asm volatile("s_waitcnt vmcnt(0)" ::: "memory");  // own batch8 landed
    __builtin_amdgcn_s_barrier();                     // all waves' batches landed
    __builtin_amdgcn_sched_barrier(0);

    // P3: MFMA Q(avHI, bv0) with CURRENT-tile bv0, THEN read next-tile frags
    QMM(avHI, bv0, 4, 0)
    if (pf) {
      #pragma unroll
      for (int mf = 0; mf < 4; ++mf) { avLO[mf][0] = rdA(nb, mf, 0); avLO[mf][1] = rdA(nb, mf, 1); }
      #pragma unroll
      for (int nf = 0; nf < 2; ++nf) { bv0[nf][0] = rdB(nb, nf, 0); bv0[nf][1] = rdB(nb, nf, 1); }
    }
  }
#undef QMM

  // epilogue: C/D map col=lane&15, row=(lane>>4)*4+j
  if constexpr (EPI == EG4) {
    const int z = n0 >> 10;  // uniform per block (1024 % 256 == 0)
    const float* bz = (z == 0) ? b0 : (z == 1) ? b1 : (z == 2) ? b2 : b3;
    float* fz = (z == 0) ? f0 : (z == 1) ? f1 : (z == 2) ? f2 : f3;
    #pragma unroll
    for (int nf = 0; nf < 4; ++nf) {
      const int n = (n0 & 1023) + wn * 64 + nf * 16 + (lane & 15);
      const float bb = bz[n];
      #pragma unroll
      for (int mf = 0; mf < 8; ++mf)
        #pragma unroll
        for (int j = 0; j < 4; ++j) {
          const int m = m0 + wm * 128 + mf * 16 + ((lane >> 4) << 2) + j;
          float v = acc[mf][nf][j] + bb;
          fz[(size_t)m * 1024 + n] = (z == 1) ? ftanh(v) : sigm(v);
        }
    }
  } else {
    #pragma unroll
    for (int nf = 0; nf < 4; ++nf) {
      const int n = n0 + wn * 64 + nf * 16 + (lane & 15);
      const float bb = b0[n];
      #pragma unroll
      for (int mf = 0; mf < 8; ++mf)
        #pragma unroll
        for (int j = 0; j < 4; ++j) {
          const int m = m0 + wm * 128 + mf * 16 + ((lane >> 4) << 2) + j;
          const size_t idx = (size_t)m * N + n;
          float v = acc[mf][nf][j] + bb;
          if constexpr (EPI == ESILU) {
            oB[idx] = f2b(v * sigm(v));
          } else if constexpr (EPI == EMUL) {
            oB[idx] = f2b(v * b2f(exB[idx]));
          } else {
            oF[idx] = v;
          }
        }
    }
  }
}

// ---------- launcher ----------
extern "C" void kernel_launch(void* const* d_in, const int* in_sizes, int n_in,
                              void* d_out, int out_size, void* d_ws, size_t ws_size,
                              hipStream_t stream) {
  (void)in_sizes; (void)n_in; (void)out_size; (void)ws_size;
  const int*   tokens = (const int*)d_in[0];
  const float* emb  = (const float*)d_in[1];
  const float* h0   = (const float*)d_in[2];
  const float* Wf   = (const float*)d_in[3];
  const float* bf_  = (const float*)d_in[4];
  const float* Wi   = (const float*)d_in[5];
  const float* bi_  = (const float*)d_in[6];
  const float* Wig  = (const float*)d_in[7];
  const float* big_ = (const float*)d_in[8];
  const float* Wog  = (const float*)d_in[9];
  const float* bog_ = (const float*)d_in[10];
  const float* n1   = (const float*)d_in[11];
  const float* n2   = (const float*)d_in[12];
  const float* Wfc  = (const float*)d_in[13];
  const float* bfc_ = (const float*)d_in[14];
  const float* Wfa  = (const float*)d_in[15];
  const float* bfa_ = (const float*)d_in[16];
  const float* Wfo  = (const float*)d_in[17];
  const float* bfo_ = (const float*)d_in[18];
  const float* nl_  = (const float*)d_in[19];
  const float* Wout = (const float*)d_in[20];
  const float* bout_= (const float*)d_in[21];
  float* out = (float*)d_out;

  char* p = (char*)d_ws;
  auto alloc = [&](size_t bytes) {
    char* r = p; p += (bytes + 255) & ~(size_t)255; return r;
  };
  u16* wbGates = (u16*)alloc((size_t)4 * DIMN * DIMN * 2);  // [4*1024,1024]
  u16* wbWfc  = (u16*)alloc((size_t)FFD * DIMN * 2);
  u16* wbWfa  = (u16*)alloc((size_t)FFD * DIMN * 2);
  u16* wbWfo  = (u16*)alloc((size_t)FFD * DIMN * 2);
  u16* wbWout = (u16*)alloc((size_t)VOCAB * DIMN * 2);
  float* x    = (float*)alloc((size_t)MROWS * DIMN * 4);
  u16* hin    = (u16*)alloc((size_t)MROWS * DIMN * 2);
  float* fbuf = (float*)alloc((size_t)MROWS * DIMN * 4);
  float* tibuf= (float*)alloc((size_t)MROWS * DIMN * 4);
  float* ggbuf= (float*)alloc((size_t)MROWS * DIMN * 4);
  float* oobuf= (float*)alloc((size_t)MROWS * DIMN * 4);
  // FFN intermediates alias the (then-dead) gate buffers:
  u16* sa = (u16*)fbuf;                                   // [4096,4096] bf16
  u16* ub = (u16*)((char*)fbuf + (size_t)MROWS * FFD * 2);// [4096,4096] bf16
  float* Ac    = (float*)alloc((size_t)2 * NCHUNK * DIMN * 4);
  float* Vc    = (float*)alloc((size_t)2 * NCHUNK * DIMN * 4);
  float* carry = (float*)alloc((size_t)2 * NCHUNK * DIMN * 4);

  auto cvt = [&](const float* src, u16* dst, size_t nelem) {
    k_cvt<<<dim3((unsigned)(nelem / 2048)), dim3(256), 0, stream>>>(
        (const f32x4*)src, (u16x8*)dst);
  };

  k_embed<<<dim3(MROWS), dim3(256), 0, stream>>>(tokens, emb, x);

  for (int L = 0; L < D_LAYERS; ++L) {
    const size_t oDD = (size_t)L * DIMN * DIMN;
    const size_t oFD = (size_t)L * FFD * DIMN;
    cvt(Wf  + oDD, wbGates + (size_t)0 * DIMN * DIMN, (size_t)DIMN * DIMN);
    cvt(Wi  + oDD, wbGates + (size_t)1 * DIMN * DIMN, (size_t)DIMN * DIMN);
    cvt(Wig + oDD, wbGates + (size_t)2 * DIMN * DIMN, (size_t)DIMN * DIMN);
    cvt(Wog + oDD, wbGates + (size_t)3 * DIMN * DIMN, (size_t)DIMN * DIMN);
    cvt(Wfc + oFD, wbWfc, (size_t)FFD * DIMN);
    cvt(Wfa + oFD, wbWfa, (size_t)FFD * DIMN);
    cvt(Wfo + oFD, wbWfo, (size_t)FFD * DIMN);

    k_rms<<<dim3(MROWS), dim3(256), 0, stream>>>(x, n1 + (size_t)L * DIMN, hin);

    // fused 4-gate GEMM: [4096,1024] @ [4096,1024]^T, route by n>>10
    gemm256<EG4><<<dim3(256), dim3(512), 0, stream>>>(
        hin, wbGates,
        bf_ + (size_t)L * DIMN, bi_ + (size_t)L * DIMN,
        big_ + (size_t)L * DIMN, bog_ + (size_t)L * DIMN,
        fbuf, tibuf, ggbuf, oobuf,
        nullptr, nullptr, nullptr, 4096, DIMN, 16);

    k_scanA<<<dim3(512), dim3(256), 0, stream>>>(fbuf, tibuf, ggbuf, Ac, Vc);
    k_scanB<<<dim3(8), dim3(256), 0, stream>>>(Ac, Vc, h0 + (size_t)L * DIMN, carry);
    k_scanC<<<dim3(512), dim3(256), 0, stream>>>(fbuf, tibuf, ggbuf, oobuf, carry, x);

    k_rms<<<dim3(MROWS), dim3(256), 0, stream>>>(x, n2 + (size_t)L * DIMN, hin);

    gemm256<ESILU><<<dim3(256), dim3(512), 0, stream>>>(
        hin, wbWfa,
        bfa_ + (size_t)L * FFD, nullptr, nullptr, nullptr,
        nullptr, nullptr, nullptr, nullptr,
        sa, nullptr, nullptr, FFD, DIMN, 16);

    gemm256<EMUL><<<dim3(256), dim3(512), 0, stream>>>(
        hin, wbWfc,
        bfc_ + (size_t)L * FFD, nullptr, nullptr, nullptr,
        nullptr, nullptr, nullptr, nullptr,
        ub, sa, nullptr, FFD, DIMN, 16);

    gemm_bt<64, EPI_RES_F32><<<dim3(32, 16), dim3(256), 0, stream>>>(
        ub, wbWfo,
        bfo_ + (size_t)L * DIMN,
        x, nullptr, nullptr, x, DIMN, FFD);
  }

  cvt(Wout, wbWout, (size_t)VOCAB * DIMN);
  k_rms<<<dim3(MROWS), dim3(256), 0, stream>>>(x, nl_, hin);
  gemm256<EVOC><<<dim3(2000), dim3(512), 0, stream>>>(
      hin, wbWout,
      bout_, nullptr, nullptr, nullptr,
      nullptr, nullptr, nullptr, nullptr,
      nullptr, nullptr, out, VOCAB, DIMN, 16);
}

// Round 6
// 2138.993 us; speedup vs baseline: 1.3903x; 1.2714x over previous
//
#include <hip/hip_runtime.h>
#include <hip/hip_bf16.h>
#include <cstdint>
#include <cstddef>

typedef unsigned short u16;
typedef __attribute__((ext_vector_type(4))) float f32x4;
typedef __attribute__((ext_vector_type(8))) short bf16x8;
typedef __attribute__((ext_vector_type(8))) unsigned short u16x8;
typedef __attribute__((ext_vector_type(4))) unsigned short u16x4;

#define D_LAYERS 8
#define DIMN 1024
#define FFD 4096
#define VOCAB 32000
#define MROWS 4096   /* B*S */
#define SEQ 2048
#define NCHUNK 64
#define LCHUNK 32

// ---------- helpers ----------
__device__ __forceinline__ u16 f2b(float f) {
  union { float f; unsigned u; } v; v.f = f;
  unsigned r = v.u + 0x7FFFu + ((v.u >> 16) & 1u);
  return (u16)(r >> 16);
}
__device__ __forceinline__ float b2f(u16 h) {
  union { unsigned u; float f; } v; v.u = ((unsigned)h) << 16;
  return v.f;
}
__device__ __forceinline__ float sigm(float x) { return 1.f / (1.f + __expf(-x)); }
__device__ __forceinline__ float ftanh(float x) {
  float e = __expf(2.f * x);          // inf for large x -> 1; 0 for very neg -> -1
  return 1.f - 2.f / (e + 1.f);
}

// async global->LDS, 16B per lane. LDS dest is wave-uniform base + lane*16 (HW).
__device__ __forceinline__ void async16(const void* g, void* l) {
  auto gp = reinterpret_cast<const __attribute__((address_space(1))) char*>(
      reinterpret_cast<uintptr_t>(g));
  auto lp = reinterpret_cast<__attribute__((address_space(3))) char*>(
      reinterpret_cast<uintptr_t>(l));
  __builtin_amdgcn_global_load_lds(gp, lp, 16, 0, 0);
}

__device__ __forceinline__ float blk_sum(float v) {
  __shared__ float sm[4];
  #pragma unroll
  for (int o = 32; o > 0; o >>= 1) v += __shfl_xor(v, o);
  if ((threadIdx.x & 63) == 0) sm[threadIdx.x >> 6] = v;
  __syncthreads();
  float r = sm[0] + sm[1] + sm[2] + sm[3];
  __syncthreads();
  return r;
}

// ---------- small kernels ----------
__global__ __launch_bounds__(256) void k_cvt(const f32x4* __restrict__ in,
                                             u16x8* __restrict__ out) {
  size_t i = (size_t)blockIdx.x * 256 + threadIdx.x;
  f32x4 a = in[i * 2], b = in[i * 2 + 1];
  u16x8 o;
  o[0] = f2b(a[0]); o[1] = f2b(a[1]); o[2] = f2b(a[2]); o[3] = f2b(a[3]);
  o[4] = f2b(b[0]); o[5] = f2b(b[1]); o[6] = f2b(b[2]); o[7] = f2b(b[3]);
  out[i] = o;
}

// converts one layer's 7 weight tensors in one launch (8192 blocks x 2048 elems)
__global__ __launch_bounds__(256) void k_cvt7(
    const float* __restrict__ Wf, const float* __restrict__ Wi,
    const float* __restrict__ Wig, const float* __restrict__ Wog,
    const float* __restrict__ Wfc, const float* __restrict__ Wfa,
    const float* __restrict__ Wfo,
    u16* __restrict__ dGates,   // [4 x 1M] bf16, order f,i,ig,og
    u16* __restrict__ dFc, u16* __restrict__ dFa, u16* __restrict__ dFo,
    int L)
{
  const int b = blockIdx.x;  // 0..8191
  const float* src; u16* dst; size_t off;
  if (b < 2048) {
    const int g = b >> 9, r = b & 511;
    const float* s = (g == 0) ? Wf : (g == 1) ? Wi : (g == 2) ? Wig : Wog;
    src = s + (size_t)L * 1048576;
    dst = dGates + (size_t)g * 1048576;
    off = (size_t)r * 2048;
  } else if (b < 4096) {
    src = Wfc + (size_t)L * 4194304; dst = dFc; off = (size_t)(b - 2048) * 2048;
  } else if (b < 6144) {
    src = Wfa + (size_t)L * 4194304; dst = dFa; off = (size_t)(b - 4096) * 2048;
  } else {
    src = Wfo + (size_t)L * 4194304; dst = dFo; off = (size_t)(b - 6144) * 2048;
  }
  const size_t i = off + (size_t)threadIdx.x * 8;
  f32x4 a = *(const f32x4*)(src + i);
  f32x4 c = *(const f32x4*)(src + i + 4);
  u16x8 o;
  o[0] = f2b(a[0]); o[1] = f2b(a[1]); o[2] = f2b(a[2]); o[3] = f2b(a[3]);
  o[4] = f2b(c[0]); o[5] = f2b(c[1]); o[6] = f2b(c[2]); o[7] = f2b(c[3]);
  *(u16x8*)(dst + i) = o;
}

__global__ __launch_bounds__(256) void k_embed(const int* __restrict__ tok,
                                               const float* __restrict__ emb,
                                               float* __restrict__ x) {
  const int r = blockIdx.x;
  const int tk = tok[r];
  f32x4 v = ((const f32x4*)(emb + (size_t)tk * DIMN))[threadIdx.x];
  float ss = v[0]*v[0] + v[1]*v[1] + v[2]*v[2] + v[3]*v[3];
  float tot = blk_sum(ss);
  float nrm = sqrtf(tot);
  float s = (nrm > 1.f) ? (1.f / (nrm + 1e-7f)) : 1.f;
  f32x4 o = {v[0]*s, v[1]*s, v[2]*s, v[3]*s};
  ((f32x4*)(x + (size_t)r * DIMN))[threadIdx.x] = o;
}

__global__ __launch_bounds__(256) void k_rms(const float* __restrict__ x,
                                             const float* __restrict__ wgt,
                                             u16* __restrict__ out) {
  const int r = blockIdx.x;
  f32x4 v = ((const f32x4*)(x + (size_t)r * DIMN))[threadIdx.x];
  float ss = v[0]*v[0] + v[1]*v[1] + v[2]*v[2] + v[3]*v[3];
  float tot = blk_sum(ss);
  float sc = rsqrtf(tot * (1.f / DIMN) + 1e-6f);
  f32x4 w = ((const f32x4*)wgt)[threadIdx.x];
  u16x4 o;
  o[0] = f2b(v[0] * sc * w[0]);
  o[1] = f2b(v[1] * sc * w[1]);
  o[2] = f2b(v[2] * sc * w[2]);
  o[3] = f2b(v[3] * sc * w[3]);
  ((u16x4*)(out + (size_t)r * DIMN))[threadIdx.x] = o;
}

// scan phase A: per-chunk aggregates (A = prod f, V = chunk-local scan end)
__global__ __launch_bounds__(256) void k_scanA(const float* __restrict__ f,
                                               const float* __restrict__ v,
                                               float* __restrict__ Ac,
                                               float* __restrict__ Vc) {
  const int bx = blockIdx.x;              // b*256 + c*4 + dg
  const int dg = bx & 3, c = (bx >> 2) & 63, b = bx >> 8;
  const int d = dg * 256 + threadIdx.x;
  const size_t base = ((size_t)(b * SEQ + c * LCHUNK)) * DIMN + d;
  float a = 1.f, h = 0.f;
  #pragma unroll 4
  for (int t = 0; t < LCHUNK; ++t) {
    size_t ix = base + (size_t)t * DIMN;
    float fv = f[ix];
    h = fv * h + v[ix];
    a *= fv;
  }
  const size_t ci = ((size_t)(b * NCHUNK + c)) * DIMN + d;
  Ac[ci] = a; Vc[ci] = h;
}

// scan phase B: exclusive scan over chunks, init = h0
__global__ __launch_bounds__(256) void k_scanB(const float* __restrict__ Ac,
                                               const float* __restrict__ Vc,
                                               const float* __restrict__ h0,
                                               float* __restrict__ carry) {
  const int idx = blockIdx.x * 256 + threadIdx.x;  // 0..2047
  const int b = idx >> 10, d = idx & 1023;
  float h = h0[d];
  for (int c = 0; c < NCHUNK; ++c) {
    size_t ci = ((size_t)(b * NCHUNK + c)) * DIMN + d;
    carry[ci] = h;
    h = Ac[ci] * h + Vc[ci];
  }
}

// scan phase C: recompute with carry-in, y = tanh(h)*o, x += y
__global__ __launch_bounds__(256) void k_scanC(const float* __restrict__ f,
                                               const float* __restrict__ v,
                                               const float* __restrict__ oo,
                                               const float* __restrict__ carry,
                                               float* __restrict__ x) {
  const int bx = blockIdx.x;
  const int dg = bx & 3, c = (bx >> 2) & 63, b = bx >> 8;
  const int d = dg * 256 + threadIdx.x;
  const size_t base = ((size_t)(b * SEQ + c * LCHUNK)) * DIMN + d;
  float h = carry[((size_t)(b * NCHUNK + c)) * DIMN + d];
  for (int t = 0; t < LCHUNK; ++t) {
    size_t ix = base + (size_t)t * DIMN;
    float fv = f[ix];
    h = fv * h + v[ix];
    x[ix] += ftanh(h) * oo[ix];
  }
}

// ---------- 128-tile GEMM (m97 structure, proven: 883 TF on vocab) ----------
constexpr int EPI_SILU_BF = 1, EPI_MUL_BF = 2, EPI_RES_F32 = 3, EPI_BIAS_F32 = 4;

template<int BN_T, int EPI>
__global__ __launch_bounds__(256, 2)
void gemm_bt(const u16* __restrict__ A,
             const u16* __restrict__ B0,
             const float* __restrict__ bias0,
             float* __restrict__ oF0,
             u16* __restrict__ oB,
             const u16* __restrict__ exB, const float* __restrict__ exF,
             int N, int K)
{
  constexpr int MF = (BN_T == 128) ? 4 : 2;
  constexpr int WAVES_N = (BN_T == 128) ? 2 : 1;
  constexpr int ISS_B = BN_T / 32;
  __shared__ __align__(16) u16 As[128 * 64];
  __shared__ __align__(16) u16 Bs[BN_T * 64];
  const int tid = threadIdx.x;
  const int w = tid >> 6, lane = tid & 63;
  const int wm = w / WAVES_N, wn = w % WAVES_N;
  const int m0 = blockIdx.x * 128;
  const int n0 = blockIdx.y * BN_T;

  const u16* Bw = B0;
  const float* bias = bias0;
  float* oF = oF0;

  const f32x4 zero = {0.f, 0.f, 0.f, 0.f};
  f32x4 acc[MF][4];
  #pragma unroll
  for (int mf = 0; mf < MF; ++mf)
    #pragma unroll
    for (int nf = 0; nf < 4; ++nf) acc[mf][nf] = zero;

  for (int kt = 0; kt < K; kt += 64) {
    #pragma unroll
    for (int i = 0; i < 4; ++i) {
      int p = i * 4096 + w * 1024 + lane * 16;
      int r = p >> 7;
      int cs = (p & 127) ^ ((r & 7) << 4);
      async16(A + ((size_t)(m0 + r) * K + kt) + (cs >> 1),
              (char*)As + i * 4096 + w * 1024);
    }
    #pragma unroll
    for (int i = 0; i < ISS_B; ++i) {
      int p = i * 4096 + w * 1024 + lane * 16;
      int r = p >> 7;
      int cs = (p & 127) ^ ((r & 7) << 4);
      async16(Bw + ((size_t)(n0 + r) * K + kt) + (cs >> 1),
              (char*)Bs + i * 4096 + w * 1024);
    }
    __syncthreads();
    #pragma unroll
    for (int ks = 0; ks < 2; ++ks) {
      bf16x8 av[MF], bv[4];
      const int cbase = ks * 64 + ((lane >> 4) << 4);
      #pragma unroll
      for (int mf = 0; mf < MF; ++mf) {
        int r = wm * (MF * 16) + mf * 16 + (lane & 15);
        av[mf] = *(const bf16x8*)((const char*)As + r * 128 + (cbase ^ ((r & 7) << 4)));
      }
      #pragma unroll
      for (int nf = 0; nf < 4; ++nf) {
        int r = wn * 64 + nf * 16 + (lane & 15);
        bv[nf] = *(const bf16x8*)((const char*)Bs + r * 128 + (cbase ^ ((r & 7) << 4)));
      }
      #pragma unroll
      for (int mf = 0; mf < MF; ++mf)
        #pragma unroll
        for (int nf = 0; nf < 4; ++nf)
          acc[mf][nf] = __builtin_amdgcn_mfma_f32_16x16x32_bf16(
              av[mf], bv[nf], acc[mf][nf], 0, 0, 0);
    }
    __syncthreads();
  }

  #pragma unroll
  for (int nf = 0; nf < 4; ++nf) {
    const int n = n0 + wn * 64 + nf * 16 + (lane & 15);
    const float bb = bias[n];
    #pragma unroll
    for (int mf = 0; mf < MF; ++mf) {
      #pragma unroll
      for (int j = 0; j < 4; ++j) {
        const int m = m0 + wm * (MF * 16) + mf * 16 + ((lane >> 4) << 2) + j;
        const size_t idx = (size_t)m * N + n;
        float v = acc[mf][nf][j] + bb;
        if constexpr (EPI == EPI_SILU_BF) {
          oB[idx] = f2b(v * sigm(v));
        } else if constexpr (EPI == EPI_MUL_BF) {
          oB[idx] = f2b(v * b2f(exB[idx]));
        } else if constexpr (EPI == EPI_RES_F32) {
          oF[idx] = v + exF[idx];
        } else {
          oF[idx] = v;
        }
      }
    }
  }
}

// ---------- dual-B 128-tile GEMM: two GEMMs sharing the A-tile ----------
// Same m97 loop but stages A once + two B tiles; 32 MFMA per barrier pair
// (vs 16) amortizes the barrier-drain stall. Epilogues:
//   EDG (gates, z-routed): z=0: (Wi,Wig) -> v = tanh(va)*sig(vb)  [1 f32 buf]
//                          z=1: (Wf,Wog) -> f = sig(va), o = sig(vb)
//   EDF (ffn-up): (Wfa,Wfc) -> u = vb * silu(va)  [bf16]
constexpr int EDG = 0, EDF = 1;

template<int EPI>
__global__ __launch_bounds__(256, 2)
void gemm_dual(const u16* __restrict__ A,
               const u16* __restrict__ Ba0, const u16* __restrict__ Bb0,
               const u16* __restrict__ Ba1, const u16* __restrict__ Bb1,
               const float* __restrict__ ba0, const float* __restrict__ bb0,
               const float* __restrict__ ba1, const float* __restrict__ bb1,
               float* __restrict__ oV,          // z=0 product (gates)
               float* __restrict__ oFa, float* __restrict__ oFb, // z=1 pair
               u16* __restrict__ oU,            // ffn-up bf16
               int N, int K)
{
  __shared__ __align__(16) u16 As[128 * 64];
  __shared__ __align__(16) u16 Bsa[128 * 64];
  __shared__ __align__(16) u16 Bsb[128 * 64];
  const int tid = threadIdx.x;
  const int w = tid >> 6, lane = tid & 63;
  const int wm = w >> 1, wn = w & 1;
  const int m0 = blockIdx.x * 128;
  const int n0 = blockIdx.y * 128;
  const int z = blockIdx.z;

  const u16* Ba = (EPI == EDG && z) ? Ba1 : Ba0;
  const u16* Bb = (EPI == EDG && z) ? Bb1 : Bb0;
  const float* ba = (EPI == EDG && z) ? ba1 : ba0;
  const float* bb = (EPI == EDG && z) ? bb1 : bb0;

  const f32x4 zero = {0.f, 0.f, 0.f, 0.f};
  f32x4 accA[4][4], accB[4][4];
  #pragma unroll
  for (int mf = 0; mf < 4; ++mf)
    #pragma unroll
    for (int nf = 0; nf < 4; ++nf) { accA[mf][nf] = zero; accB[mf][nf] = zero; }

  for (int kt = 0; kt < K; kt += 64) {
    #pragma unroll
    for (int i = 0; i < 4; ++i) {
      const int p = i * 4096 + w * 1024 + lane * 16;
      const int r = p >> 7;
      const int cs = (p & 127) ^ ((r & 7) << 4);
      async16(A  + ((size_t)(m0 + r) * K + kt) + (cs >> 1),
              (char*)As + i * 4096 + w * 1024);
      async16(Ba + ((size_t)(n0 + r) * K + kt) + (cs >> 1),
              (char*)Bsa + i * 4096 + w * 1024);
      async16(Bb + ((size_t)(n0 + r) * K + kt) + (cs >> 1),
              (char*)Bsb + i * 4096 + w * 1024);
    }
    __syncthreads();
    #pragma unroll
    for (int ks = 0; ks < 2; ++ks) {
      bf16x8 av[4], bva[4], bvb[4];
      const int cbase = ks * 64 + ((lane >> 4) << 4);
      #pragma unroll
      for (int mf = 0; mf < 4; ++mf) {
        const int r = wm * 64 + mf * 16 + (lane & 15);
        av[mf] = *(const bf16x8*)((const char*)As + r * 128 + (cbase ^ ((r & 7) << 4)));
      }
      #pragma unroll
      for (int nf = 0; nf < 4; ++nf) {
        const int r = wn * 64 + nf * 16 + (lane & 15);
        const int off = r * 128 + (cbase ^ ((r & 7) << 4));
        bva[nf] = *(const bf16x8*)((const char*)Bsa + off);
        bvb[nf] = *(const bf16x8*)((const char*)Bsb + off);
      }
      #pragma unroll
      for (int mf = 0; mf < 4; ++mf)
        #pragma unroll
        for (int nf = 0; nf < 4; ++nf) {
          accA[mf][nf] = __builtin_amdgcn_mfma_f32_16x16x32_bf16(
              av[mf], bva[nf], accA[mf][nf], 0, 0, 0);
          accB[mf][nf] = __builtin_amdgcn_mfma_f32_16x16x32_bf16(
              av[mf], bvb[nf], accB[mf][nf], 0, 0, 0);
        }
    }
    __syncthreads();
  }

  #pragma unroll
  for (int nf = 0; nf < 4; ++nf) {
    const int n = n0 + wn * 64 + nf * 16 + (lane & 15);
    const float bba = ba[n], bbb = bb[n];
    #pragma unroll
    for (int mf = 0; mf < 4; ++mf) {
      #pragma unroll
      for (int j = 0; j < 4; ++j) {
        const int m = m0 + wm * 64 + mf * 16 + ((lane >> 4) << 2) + j;
        const size_t idx = (size_t)m * N + n;
        const float va = accA[mf][nf][j] + bba;
        const float vb = accB[mf][nf][j] + bbb;
        if constexpr (EPI == EDG) {
          if (z == 0) {
            oV[idx] = ftanh(va) * sigm(vb);
          } else {
            oFa[idx] = sigm(va);
            oFb[idx] = sigm(vb);
          }
        } else {
          oU[idx] = f2b(vb * va * sigm(va));
        }
      }
    }
  }
}

// ---------- launcher ----------
extern "C" void kernel_launch(void* const* d_in, const int* in_sizes, int n_in,
                              void* d_out, int out_size, void* d_ws, size_t ws_size,
                              hipStream_t stream) {
  (void)in_sizes; (void)n_in; (void)out_size; (void)ws_size;
  const int*   tokens = (const int*)d_in[0];
  const float* emb  = (const float*)d_in[1];
  const float* h0   = (const float*)d_in[2];
  const float* Wf   = (const float*)d_in[3];
  const float* bf_  = (const float*)d_in[4];
  const float* Wi   = (const float*)d_in[5];
  const float* bi_  = (const float*)d_in[6];
  const float* Wig  = (const float*)d_in[7];
  const float* big_ = (const float*)d_in[8];
  const float* Wog  = (const float*)d_in[9];
  const float* bog_ = (const float*)d_in[10];
  const float* n1   = (const float*)d_in[11];
  const float* n2   = (const float*)d_in[12];
  const float* Wfc  = (const float*)d_in[13];
  const float* bfc_ = (const float*)d_in[14];
  const float* Wfa  = (const float*)d_in[15];
  const float* bfa_ = (const float*)d_in[16];
  const float* Wfo  = (const float*)d_in[17];
  const float* bfo_ = (const float*)d_in[18];
  const float* nl_  = (const float*)d_in[19];
  const float* Wout = (const float*)d_in[20];
  const float* bout_= (const float*)d_in[21];
  float* out = (float*)d_out;

  char* p = (char*)d_ws;
  auto alloc = [&](size_t bytes) {
    char* r = p; p += (bytes + 255) & ~(size_t)255; return r;
  };
  u16* wbGates = (u16*)alloc((size_t)4 * DIMN * DIMN * 2);  // f,i,ig,og
  u16* wbWfc  = (u16*)alloc((size_t)FFD * DIMN * 2);
  u16* wbWfa  = (u16*)alloc((size_t)FFD * DIMN * 2);
  u16* wbWfo  = (u16*)alloc((size_t)FFD * DIMN * 2);
  u16* wbWout = (u16*)alloc((size_t)VOCAB * DIMN * 2);
  float* x    = (float*)alloc((size_t)MROWS * DIMN * 4);
  u16* hin    = (u16*)alloc((size_t)MROWS * DIMN * 2);
  float* fbuf = (float*)alloc((size_t)MROWS * DIMN * 4);
  float* vbuf = (float*)alloc((size_t)MROWS * DIMN * 4);
  float* oobuf= (float*)alloc((size_t)MROWS * DIMN * 4);
  u16* ub     = (u16*)alloc((size_t)MROWS * FFD * 2);
  float* Ac    = (float*)alloc((size_t)2 * NCHUNK * DIMN * 4);
  float* Vc    = (float*)alloc((size_t)2 * NCHUNK * DIMN * 4);
  float* carry = (float*)alloc((size_t)2 * NCHUNK * DIMN * 4);

  u16* wbWf  = wbGates;
  u16* wbWi  = wbGates + (size_t)1 * DIMN * DIMN;
  u16* wbWig = wbGates + (size_t)2 * DIMN * DIMN;
  u16* wbWog = wbGates + (size_t)3 * DIMN * DIMN;

  k_embed<<<dim3(MROWS), dim3(256), 0, stream>>>(tokens, emb, x);

  for (int L = 0; L < D_LAYERS; ++L) {
    k_cvt7<<<dim3(8192), dim3(256), 0, stream>>>(
        Wf, Wi, Wig, Wog, Wfc, Wfa, Wfo,
        wbGates, wbWfc, wbWfa, wbWfo, L);

    k_rms<<<dim3(MROWS), dim3(256), 0, stream>>>(x, n1 + (size_t)L * DIMN, hin);

    // fused gate pairs: z=0 (Wi,Wig)->vbuf ; z=1 (Wf,Wog)->fbuf,oobuf
    gemm_dual<EDG><<<dim3(32, 8, 2), dim3(256), 0, stream>>>(
        hin, wbWi, wbWig, wbWf, wbWog,
        bi_ + (size_t)L * DIMN, big_ + (size_t)L * DIMN,
        bf_ + (size_t)L * DIMN, bog_ + (size_t)L * DIMN,
        vbuf, fbuf, oobuf, nullptr, DIMN, DIMN);

    k_scanA<<<dim3(512), dim3(256), 0, stream>>>(fbuf, vbuf, Ac, Vc);
    k_scanB<<<dim3(8), dim3(256), 0, stream>>>(Ac, Vc, h0 + (size_t)L * DIMN, carry);
    k_scanC<<<dim3(512), dim3(256), 0, stream>>>(fbuf, vbuf, oobuf, carry, x);

    k_rms<<<dim3(MROWS), dim3(256), 0, stream>>>(x, n2 + (size_t)L * DIMN, hin);

    // fused FFN-up: (Wfa,Wfc) -> u = fc * silu(fa)
    gemm_dual<EDF><<<dim3(32, 32, 1), dim3(256), 0, stream>>>(
        hin, wbWfa, wbWfc, nullptr, nullptr,
        bfa_ + (size_t)L * FFD, bfc_ + (size_t)L * FFD, nullptr, nullptr,
        nullptr, nullptr, nullptr, ub, FFD, DIMN);

    gemm_bt<64, EPI_RES_F32><<<dim3(32, 16), dim3(256), 0, stream>>>(
        ub, wbWfo,
        bfo_ + (size_t)L * DIMN,
        x, nullptr, nullptr, x, DIMN, FFD);
  }

  k_cvt<<<dim3(16000), dim3(256), 0, stream>>>((const f32x4*)Wout, (u16x8*)wbWout);
  k_rms<<<dim3(MROWS), dim3(256), 0, stream>>>(x, nl_, hin);
  gemm_bt<128, EPI_BIAS_F32><<<dim3(32, 250), dim3(256), 0, stream>>>(
      hin, wbWout,
      bout_,
      out, nullptr, nullptr, nullptr, VOCAB, DIMN);
}